// Round 12
// baseline (2654.291 us; speedup 1.0000x reference)
//
#include <hip/hip_runtime.h>
#include <cstdint>
#include <cstddef>

// ---------------------------------------------------------------------------
// Gemma 2-layer forward, MI355X. Round 12: gemm8p v3 — read-ahead pipelined
//   phases (ping-pong frag regs, counted lgkmcnt, 1 barrier/phase, vmcnt(2)
//   gates at ph0/ph2/ph3, peeled tail). Everything else = round 11.
// ---------------------------------------------------------------------------

typedef unsigned short u16;
typedef __bf16 bf16x8 __attribute__((ext_vector_type(8)));
typedef float f32x4 __attribute__((ext_vector_type(4)));

#define S_LEN 2048
#define HDIM  2048
#define QKV_N 2560
#define HD    256
#define ATT_SCALE 0.0625f

__device__ __forceinline__ u16 f2b(float f) {
  union { float f; unsigned u; } x; x.f = f;
  unsigned r = x.u + 0x7FFFu + ((x.u >> 16) & 1u);
  return (u16)(r >> 16);
}
__device__ __forceinline__ float b2f(u16 b) {
  union { unsigned u; float f; } x; x.u = ((unsigned)b) << 16;
  return x.f;
}

typedef __attribute__((address_space(1))) void as1_void;
typedef __attribute__((address_space(3))) void as3_void;
__device__ __forceinline__ void gload_lds16(const void* g, void* l) {
  __builtin_amdgcn_global_load_lds((as1_void*)((void*)g), (as3_void*)l, 16, 0, 0);
}

__device__ __forceinline__ void barrier_raw() {
  __builtin_amdgcn_sched_barrier(0);
  asm volatile("" ::: "memory");
  __builtin_amdgcn_s_barrier();
  asm volatile("" ::: "memory");
  __builtin_amdgcn_sched_barrier(0);
}

__device__ __forceinline__ float gelu_tanh(float x) {
  float t = tanhf(0.7978845608028654f * (x + 0.044715f * x * x * x));
  return 0.5f * x * (1.0f + t);
}

// ---------------------------------------------------------------------------
__global__ void cvt_kernel(const float* __restrict__ in, u16* __restrict__ out, int n4) {
  int idx = blockIdx.x * blockDim.x + threadIdx.x;
  int stride = gridDim.x * blockDim.x;
  for (int i = idx; i < n4; i += stride) {
    f32x4 v = reinterpret_cast<const f32x4*>(in)[i];
    unsigned lo = (unsigned)f2b(v[0]) | ((unsigned)f2b(v[1]) << 16);
    unsigned hi = (unsigned)f2b(v[2]) | ((unsigned)f2b(v[3]) << 16);
    uint2 p; p.x = lo; p.y = hi;
    reinterpret_cast<uint2*>(out)[i] = p;
  }
}

// ---------------------------------------------------------------------------
template<bool OBF>
__launch_bounds__(256)
__global__ void rms_kernel(const float* in, const float* w, u16* obf, float* of) {
  const int row = blockIdx.x;
  const int tid = threadIdx.x;
  const float* x = in + (size_t)row * HDIM;
  f32x4 v0 = reinterpret_cast<const f32x4*>(x)[tid];
  f32x4 v1 = reinterpret_cast<const f32x4*>(x)[tid + 256];
  float ss = v0[0]*v0[0] + v0[1]*v0[1] + v0[2]*v0[2] + v0[3]*v0[3]
           + v1[0]*v1[0] + v1[1]*v1[1] + v1[2]*v1[2] + v1[3]*v1[3];
#pragma unroll
  for (int off = 32; off > 0; off >>= 1) ss += __shfl_xor(ss, off);
  __shared__ float sred[4];
  if ((tid & 63) == 0) sred[tid >> 6] = ss;
  __syncthreads();
  float tot = sred[0] + sred[1] + sred[2] + sred[3];
  float r = rsqrtf(tot * (1.0f / (float)HDIM) + 1e-6f);
  f32x4 w0 = reinterpret_cast<const f32x4*>(w)[tid];
  f32x4 w1 = reinterpret_cast<const f32x4*>(w)[tid + 256];
#pragma unroll
  for (int j = 0; j < 4; ++j) {
    float a = v0[j] * r * (1.0f + w0[j]);
    float b = v1[j] * r * (1.0f + w1[j]);
    if (OBF) {
      obf[(size_t)row * HDIM + tid * 4 + j]        = f2b(a);
      obf[(size_t)row * HDIM + 1024 + tid * 4 + j] = f2b(b);
    } else {
      of[(size_t)row * HDIM + tid * 4 + j]        = a;
      of[(size_t)row * HDIM + 1024 + tid * 4 + j] = b;
    }
  }
}

// ---------------------------------------------------------------------------
// gemm128 (m97 replica): qkv + o-proj. EPI 0: Cb=bf16  3: split-K partial
// ---------------------------------------------------------------------------
template<int EPI>
__launch_bounds__(256, 4)
__global__ void gemm128(const u16* __restrict__ A, const u16* __restrict__ B,
                        u16* Cb, float* Cf, int M, int N, int K,
                        int lda, int ldb, int ldc) {
  __shared__ alignas(16) u16 As[128 * 64];
  __shared__ alignas(16) u16 Bs[128 * 64];
  const int tid = threadIdx.x;
  const int lane = tid & 63, w = tid >> 6;
  const int l16 = lane & 15, lhi = lane >> 4;
  const int wr = w >> 1, wc = w & 1;

  const int nwg = gridDim.x, bid = blockIdx.x;
  const int q = nwg >> 3, rm = nwg & 7, xc = bid & 7, li = bid >> 3;
  const int swz = (xc < rm ? xc * (q + 1) : rm * (q + 1) + (xc - rm) * q) + li;
  const int MT = M >> 7;
  const int m0 = (swz % MT) << 7;
  const int n0 = (swz / MT) << 7;
  const int kbase = blockIdx.z * K;

  const u16 *sA[4], *sB[4];
#pragma unroll
  for (int c = 0; c < 4; ++c) {
    int o = c * 4096 + w * 1024 + lane * 16;
    int r = o >> 7, s = (o >> 4) & 7;
    int ks = (s ^ (r & 7)) << 3;
    sA[c] = A + (size_t)(m0 + r) * lda + kbase + ks;
    sB[c] = B + (size_t)(n0 + r) * ldb + kbase + ks;
  }

  int aoff[2][4], boff[2][4];
#pragma unroll
  for (int kf = 0; kf < 2; ++kf)
#pragma unroll
    for (int f = 0; f < 4; ++f) {
      int ra = wr * 64 + f * 16 + l16;
      int rb = wc * 64 + f * 16 + l16;
      int sl = ((kf * 4 + lhi) ^ (l16 & 7)) << 4;
      aoff[kf][f] = ra * 128 + sl;
      boff[kf][f] = rb * 128 + sl;
    }

  f32x4 acc[4][4] = {};
  const char* pa = (const char*)As;
  const char* pb = (const char*)Bs;

  for (int k0 = 0; k0 < K; k0 += 64) {
#pragma unroll
    for (int c = 0; c < 4; ++c)
      gload_lds16(sA[c] + k0, (char*)As + c * 4096 + w * 1024);
#pragma unroll
    for (int c = 0; c < 4; ++c)
      gload_lds16(sB[c] + k0, (char*)Bs + c * 4096 + w * 1024);
    __syncthreads();
#pragma unroll
    for (int kf = 0; kf < 2; ++kf) {
      bf16x8 af[4], bf[4];
#pragma unroll
      for (int f = 0; f < 4; ++f) af[f] = *reinterpret_cast<const bf16x8*>(pa + aoff[kf][f]);
#pragma unroll
      for (int f = 0; f < 4; ++f) bf[f] = *reinterpret_cast<const bf16x8*>(pb + boff[kf][f]);
#pragma unroll
      for (int mf = 0; mf < 4; ++mf)
#pragma unroll
        for (int nf = 0; nf < 4; ++nf)
          acc[mf][nf] = __builtin_amdgcn_mfma_f32_16x16x32_bf16(af[mf], bf[nf], acc[mf][nf], 0, 0, 0);
    }
    __syncthreads();
  }

#pragma unroll
  for (int mf = 0; mf < 4; ++mf)
#pragma unroll
    for (int nf = 0; nf < 4; ++nf)
#pragma unroll
      for (int rr = 0; rr < 4; ++rr) {
        int row = m0 + wr * 64 + mf * 16 + lhi * 4 + rr;
        int col = n0 + wc * 64 + nf * 16 + l16;
        size_t idx = (size_t)row * ldc + col;
        float v = acc[mf][nf][rr];
        if (EPI == 0) Cb[idx] = f2b(v);
        else          Cf[(size_t)blockIdx.z * ((size_t)M * N) + idx] = v;
      }
}

// ---------------------------------------------------------------------------
// gemm8p v3 — 8-wave 256^2, BK=64, 2x64KB dbuf, READ-AHEAD pipelined phases.
// Phase p: issue reads R(p+1) (ping-pong regs) | stage 1 unit of t+1 |
//   lgkmcnt(#issued) => R(p) landed | sched_barrier | setprio 16 MFMA |
//   vmcnt gate | ONE barrier.
// Stage order: u0=A-mh0@ph0, u1=B-kh0@ph1, u2=A-mh1@ph2, u3=B-kh1@ph3.
// Read needs: R(0):u0,u1  R(1):u2  R(2):u3  R(3):-  (R(0) of t+1 at ph3).
// Gates: VMW(2) end of ph0 (u3), ph2 (u0,u1 of t+1), ph3 (u2 of t+1).
// Tail peeled: ph0 VMW(0); ph3 lgkm(0), no reads/stage.
// EPI 0: Cb=bf16  2: Cb=gelu(Cb)*acc  3: Cf[z*M*N+idx]=acc
// ---------------------------------------------------------------------------
#define VMW(N) asm volatile("s_waitcnt vmcnt(" #N ")" ::: "memory")
#define LGKM(N) do { asm volatile("s_waitcnt lgkmcnt(" #N ")" ::: "memory"); \
                     __builtin_amdgcn_sched_barrier(0); } while (0)

#define STAGE_A(T, U)                                                         \
  { char* d_ = smem + (((size_t)((T) & 1)) << 16) + (U) * 16384 + w * 1024;   \
    const u16* s_ = pA + (size_t)(T) * 64 + (U) * A128;                       \
    gload_lds16(s_, d_); gload_lds16(s_ + A64, d_ + 8192); }

#define STAGE_B(T, KH)                                                        \
  { char* d_ = smem + (((size_t)((T) & 1)) << 16) + 32768 + (KH) * 16384 + w * 1024; \
    const u16* s_ = pB + (size_t)(T) * 64 + (KH) * 32;                        \
    gload_lds16(s_, d_); gload_lds16(s_ + B128, d_ + 8192); }

#define RDA(DST, CBUF, KH, MH)                                                \
  { const char* va_ = (CBUF) + ((KH) ? pa1 : pa0) + (MH) * 16384;             \
    DST[0] = *reinterpret_cast<const bf16x8*>(va_);                           \
    DST[1] = *reinterpret_cast<const bf16x8*>(va_ + 2048);                    \
    DST[2] = *reinterpret_cast<const bf16x8*>(va_ + 4096);                    \
    DST[3] = *reinterpret_cast<const bf16x8*>(va_ + 6144); }

#define RDB(DST, CBUF, KH)                                                    \
  { const char* vb_ = (CBUF) + qb + (KH) * 16384;                             \
    DST[0] = *reinterpret_cast<const bf16x8*>(vb_);                           \
    DST[1] = *reinterpret_cast<const bf16x8*>(vb_ + 1024);                    \
    DST[2] = *reinterpret_cast<const bf16x8*>(vb_ + 2048);                    \
    DST[3] = *reinterpret_cast<const bf16x8*>(vb_ + 3072); }

#define MFMA16(FA, FB, MH)                                                    \
  { __builtin_amdgcn_s_setprio(1);                                            \
    _Pragma("unroll")                                                         \
    for (int nf = 0; nf < 4; ++nf) {                                          \
      acc[(MH)*4+0][nf] = __builtin_amdgcn_mfma_f32_16x16x32_bf16(FA[0], FB[nf], acc[(MH)*4+0][nf], 0,0,0); \
      acc[(MH)*4+1][nf] = __builtin_amdgcn_mfma_f32_16x16x32_bf16(FA[1], FB[nf], acc[(MH)*4+1][nf], 0,0,0); \
      acc[(MH)*4+2][nf] = __builtin_amdgcn_mfma_f32_16x16x32_bf16(FA[2], FB[nf], acc[(MH)*4+2][nf], 0,0,0); \
      acc[(MH)*4+3][nf] = __builtin_amdgcn_mfma_f32_16x16x32_bf16(FA[3], FB[nf], acc[(MH)*4+3][nf], 0,0,0); \
    }                                                                         \
    __builtin_amdgcn_s_setprio(0); }

template<int EPI>
__launch_bounds__(512, 2)
__global__ void gemm8p(const u16* __restrict__ A, const u16* __restrict__ B,
                       u16* Cb, float* Cf, int M, int N, int Ks,
                       int lda, int ldb, int ldc) {
  extern __shared__ char smem[];   // 2 x 64KB
  const int tid = threadIdx.x;
  const int lane = tid & 63, w = tid >> 6;
  const int l16 = lane & 15, lhi = lane >> 4;
  const int wr = w >> 2, wc = w & 3;

  const int nwg = gridDim.x, bid = blockIdx.x;
  const int q = nwg >> 3, rm = nwg & 7, xc = bid & 7, li = bid >> 3;
  const int swz = (xc < rm ? xc * (q + 1) : rm * (q + 1) + (xc - rm) * q) + li;
  const int MT = M >> 8;
  const int m0 = (swz % MT) << 8;
  const int n0 = (swz / MT) << 8;
  const int kbase = blockIdx.z * Ks;
  const int NT = Ks >> 6;

  const size_t A64  = (size_t)lda * 64;
  const size_t A128 = (size_t)lda * 128;
  const size_t B128 = (size_t)ldb * 128;

  const u16 *pA, *pB;
  {
    int o = w * 1024 + lane * 16;
    int rA = o >> 7, sA = (o >> 4) & 7;
    pA = A + (size_t)(m0 + rA) * lda + kbase + ((sA ^ (rA & 7)) << 3);
    int rB = o >> 6, sB = (o >> 4) & 3;
    pB = B + (size_t)(n0 + rB) * ldb + kbase + ((sB ^ ((rB >> 1) & 3)) << 3);
  }

  const int pa0 = wr * 8192 + l16 * 128 + ((lhi ^ (l16 & 7)) << 4);
  const int pa1 = wr * 8192 + l16 * 128 + (((4 + lhi) ^ (l16 & 7)) << 4);
  const int qb  = 32768 + wc * 4096 + l16 * 64 + ((lhi ^ ((l16 >> 1) & 3)) << 4);

  f32x4 acc[8][4] = {};
  bf16x8 fap[4], faq[4], fb0[4], fb1[4];

  // prologue: stage tile 0 (u0=A0, u1=B0, u2=A1, u3=B1); u0..u2 landed
  STAGE_A(0, 0); STAGE_B(0, 0); STAGE_A(0, 1); STAGE_B(0, 1);
  VMW(2);
  barrier_raw();
  RDA(fap, smem, 0, 0);       // R(0): fa(kh0,mh0)
  RDB(fb0, smem, 0);          //        fb0

  for (int t = 0; t < NT - 1; ++t) {
    const char* cb = smem + (((size_t)(t & 1)) << 16);
    const char* nb = smem + (((size_t)((t + 1) & 1)) << 16);
    const int tn = t + 1;
    // ph0: MFMA(kh0,mh0); reads R(1)
    RDA(faq, cb, 0, 1);
    STAGE_A(tn, 0);
    LGKM(4);
    MFMA16(fap, fb0, 0);
    VMW(2);                    // u3(t) landed for R(2)
    barrier_raw();
    // ph1: MFMA(kh0,mh1); reads R(2)
    RDA(fap, cb, 1, 0);
    RDB(fb1, cb, 1);
    STAGE_B(tn, 0);
    LGKM(8);
    MFMA16(faq, fb0, 1);
    barrier_raw();
    // ph2: MFMA(kh1,mh0); reads R(3)
    RDA(faq, cb, 1, 1);
    STAGE_A(tn, 1);
    LGKM(4);
    MFMA16(fap, fb1, 0);
    VMW(2);                    // u0,u1(t+1) landed for R(0)'
    barrier_raw();
    // ph3: MFMA(kh1,mh1); reads R(0) of t+1 from next buffer
    RDA(fap, nb, 0, 0);
    RDB(fb0, nb, 0);
    STAGE_B(tn, 1);
    LGKM(8);
    MFMA16(faq, fb1, 1);
    VMW(2);                    // u2(t+1) landed for R(1)
    barrier_raw();
  }
  {  // tail tile NT-1: no staging
    const char* cb = smem + (((size_t)((NT - 1) & 1)) << 16);
    RDA(faq, cb, 0, 1);
    LGKM(4);
    MFMA16(fap, fb0, 0);
    VMW(0);                    // u3(NT-1) must land (no deeper stages exist)
    barrier_raw();
    RDA(fap, cb, 1, 0);
    RDB(fb1, cb, 1);
    LGKM(8);
    MFMA16(faq, fb0, 1);
    barrier_raw();
    RDA(faq, cb, 1, 1);
    LGKM(4);
    MFMA16(fap, fb1, 0);
    barrier_raw();
    LGKM(0);
    MFMA16(faq, fb1, 1);
  }

#pragma unroll
  for (int mf = 0; mf < 8; ++mf)
#pragma unroll
    for (int nf = 0; nf < 4; ++nf)
#pragma unroll
      for (int rr = 0; rr < 4; ++rr) {
        int row = m0 + (mf >> 2) * 128 + wr * 64 + (mf & 3) * 16 + lhi * 4 + rr;
        int col = n0 + wc * 64 + nf * 16 + l16;
        size_t idx = (size_t)row * ldc + col;
        float v = acc[mf][nf][rr];
        if (EPI == 0)      Cb[idx] = f2b(v);
        else if (EPI == 2) { float g = b2f(Cb[idx]); Cb[idx] = f2b(gelu_tanh(g) * v); }
        else               Cf[(size_t)blockIdx.z * ((size_t)M * N) + idx] = v;
      }
}

// h += p0 + p1 (split-K combine)
__global__ void combine_kernel(float* __restrict__ h, const float* __restrict__ p0,
                               const float* __restrict__ p1, int n4) {
  int idx = blockIdx.x * blockDim.x + threadIdx.x;
  int stride = gridDim.x * blockDim.x;
  for (int i = idx; i < n4; i += stride) {
    f32x4 a = reinterpret_cast<f32x4*>(h)[i];
    f32x4 b = reinterpret_cast<const f32x4*>(p0)[i];
    f32x4 c = reinterpret_cast<const f32x4*>(p1)[i];
    a = a + b + c;
    reinterpret_cast<f32x4*>(h)[i] = a;
  }
}

// ---------------------------------------------------------------------------
__global__ void rope_kernel(u16* qkv, const float* __restrict__ cosT, const float* __restrict__ sinT) {
  const int s = blockIdx.x, b = blockIdx.y;
  const size_t base = (size_t)(b * S_LEN + s) * QKV_N;
  for (int i = threadIdx.x; i < 9 * 128; i += 256) {
    int hh = i >> 7, d = i & 127;
    size_t off = base + (hh < 8 ? hh * 256 : 2048) + d;
    float x1 = b2f(qkv[off]), x2 = b2f(qkv[off + 128]);
    float c = cosT[s * 128 + d], sn = sinT[s * 128 + d];
    qkv[off]       = f2b(x1 * c - x2 * sn);
    qkv[off + 128] = f2b(x1 * sn + x2 * c);
  }
}

// ---------------------------------------------------------------------------
__global__ void vtrans_kernel(const u16* __restrict__ qkv, u16* __restrict__ vT) {
  __shared__ u16 t[64][65];
  const int s0 = blockIdx.x * 64, d0 = blockIdx.y * 64, b = blockIdx.z;
  for (int i = threadIdx.x; i < 4096; i += 256) {
    int r = i >> 6, c = i & 63;
    t[r][c] = qkv[(size_t)(b * S_LEN + s0 + r) * QKV_N + 2304 + d0 + c];
  }
  __syncthreads();
  for (int i = threadIdx.x; i < 4096; i += 256) {
    int r = i >> 6, c = i & 63;
    vT[(size_t)(b * HD + d0 + r) * S_LEN + s0 + c] = t[c][r];
  }
}

// ---------------------------------------------------------------------------
// Flash attention (round-11 proven): LDS-staged K/V^T, KVBLK=32, prefetch-2.
// ---------------------------------------------------------------------------
__launch_bounds__(256)
__global__ void flash_kernel(const u16* __restrict__ qkv, const u16* __restrict__ vT,
                             u16* __restrict__ outp) {
  extern __shared__ char fsm[];
  const int qt = blockIdx.x, hh = blockIdx.y, b = blockIdx.z;
  const int tid = threadIdx.x, lane = tid & 63, w = tid >> 6;
  const int l16 = lane & 15, lhi = lane >> 4;

  const u16* srcK[4]; const u16* srcV[4];
#pragma unroll
  for (int c = 0; c < 4; ++c) {
    int o = c * 4096 + tid * 16;
    int rK = o >> 9, sK = (o >> 4) & 31;
    srcK[c] = qkv + (size_t)(b * S_LEN + rK) * QKV_N + HDIM + ((sK ^ (rK & 7)) << 3);
    int dV = o >> 6, sV = (o >> 4) & 3;
    srcV[c] = vT + (size_t)(b * HD + dV) * S_LEN + ((sV ^ ((dV >> 1) & 3)) << 3);
  }
  const size_t KSTEP = (size_t)32 * QKV_N;

  u16* plds = (u16*)(fsm + 65536) + w * 640;

  bf16x8 aq[8];
  {
    const u16* qp = qkv + (size_t)(b * S_LEN + qt * 64 + w * 16 + l16) * QKV_N + hh * HD + lhi * 8;
#pragma unroll
    for (int kf = 0; kf < 8; ++kf)
      aq[kf] = *reinterpret_cast<const bf16x8*>(qp + kf * 32);
  }

  f32x4 oacc[16] = {};
  float mrow[4] = {-1e30f, -1e30f, -1e30f, -1e30f};
  float lrow[4] = {0.f, 0.f, 0.f, 0.f};
  const int rowg0 = qt * 64 + w * 16 + lhi * 4;
  const int NT = 2 * (qt + 1);
  const int m7 = l16 & 7;
  const int vcol = (lhi ^ ((l16 >> 1) & 3)) << 4;

  auto stage = [&](int t) {
    char* kb = fsm + (t & 1) * 16384;
    char* vb = fsm + 32768 + (t & 1) * 16384;
#pragma unroll
    for (int c = 0; c < 4; ++c) {
      gload_lds16(srcK[c] + (size_t)t * KSTEP, kb + c * 4096 + w * 1024);
      gload_lds16(srcV[c] + t * 32,            vb + c * 4096 + w * 1024);
    }
  };

  stage(0);
  stage(1);
  VMW(8);
  barrier_raw();

  for (int t = 0; t < NT; ++t) {
    const char* kb = fsm + (t & 1) * 16384;
    const char* vb = fsm + 32768 + (t & 1) * 16384;
    const int j0 = t * 32;

    f32x4 sacc[2] = {};
#pragma unroll
    for (int nf = 0; nf < 2; ++nf) {
      const char* rowp = kb + (nf * 16 + l16) * 512;
#pragma unroll
      for (int kf = 0; kf < 8; ++kf) {
        bf16x8 bk = *reinterpret_cast<const bf16x8*>(rowp + ((((kf << 2) + lhi) ^ m7) << 4));
        sacc[nf] = __builtin_amdgcn_mfma_f32_16x16x32_bf16(aq[kf], bk, sacc[nf], 0, 0, 0);
      }
    }

    float sval[2][4];
    float tm[4] = {-1e30f, -1e30f, -1e30f, -1e30f};
#pragma unroll
    for (int nf = 0; nf < 2; ++nf) {
      int colg = j0 + nf * 16 + l16;
#pragma unroll
      for (int r = 0; r < 4; ++r) {
        float sv = sacc[nf][r] * ATT_SCALE;
        if (colg > rowg0 + r) sv = -1e30f;
        sval[nf][r] = sv;
        tm[r] = fmaxf(tm[r], sv);
      }
    }
#pragma unroll
    for (int off = 1; off < 16; off <<= 1)
#pragma unroll
      for (int r = 0; r < 4; ++r) tm[r] = fmaxf(tm[r], __shfl_xor(tm[r], off));

    float alpha[4], psum[4] = {0.f, 0.f, 0.f, 0.f};
#pragma unroll
    for (int r = 0; r < 4; ++r) {
      float mn = fmaxf(mrow[r], tm[r]);
      alpha[r] = __expf(mrow[r] - mn);
      mrow[r] = mn;
    }
#pragma unroll
    for (int nf = 0; nf < 2; ++nf)
#pragma unroll
      for (int r = 0; r < 4; ++r) {
        float p = __expf(sval[nf][r] - mrow[r]);
        psum[r] += p;
        plds[(lhi * 4 + r) * 40 + nf * 16 + l16] = f2b(p);
      }
#pragma unroll
    for (int off = 1; off < 16; off <<= 1)
#pragma unroll
      for (int r = 0; r < 4; ++r) psum[r] += __shfl_xor(psum[r], off);
#pragma unroll
    for (int r = 0; r < 4; ++r) lrow[r] = lrow[r] * alpha[r] + psum[r];
#pragma unroll
    for (int nf2 = 0; nf2 < 16; ++nf2)
#pragma unroll
      for (int r = 0; r < 4; ++r) oacc[nf2][r] *= alpha[r];

    {
      bf16x8 pa = *reinterpret_cast<const bf16x8*>((const char*)plds + l16 * 80 + lhi * 16);
#pragma unroll
      for (int nf2 = 0; nf2 < 16; ++nf2) {
        bf16x8 bv = *reinterpret_cast<const bf16x8*>(vb + (nf2 * 16 + l16) * 64 + vcol);
        oacc[nf2] = __builtin_amdgcn_mfma_f32_16x16x32_bf16(pa, bv, oacc[nf2], 0, 0, 0);
      }
    }

    if (t + 1 < NT) {
      barrier_raw();
      if (t + 2 < NT) {
        stage(t + 2);
        VMW(8);
      } else {
        VMW(0);
      }
      barrier_raw();
    }
  }

  float inv[4];
#pragma unroll
  for (int r = 0; r < 4; ++r) inv[r] = 1.0f / lrow[r];
#pragma unroll
  for (int nf2 = 0; nf2 < 16; ++nf2)
#pragma unroll
    for (int r = 0; r < 4; ++r) {
      size_t idx = (size_t)(b * S_LEN + rowg0 + r) * HDIM + hh * HD + nf2 * 16 + l16;
      outp[idx] = f2b(oacc[nf2][r] * inv[r]);
    }
}

// ---------------------------------------------------------------------------
extern "C" void kernel_launch(void* const* d_in, const int* in_sizes, int n_in,
                              void* d_out, int out_size, void* d_ws, size_t ws_size,
                              hipStream_t stream) {
  const float* hidden = (const float*)d_in[0];
  const float* cosT   = (const float*)d_in[1];
  const float* sinT   = (const float*)d_in[2];
  const float* wq  = (const float*)d_in[6];
  const float* wk  = (const float*)d_in[7];
  const float* wv  = (const float*)d_in[8];
  const float* wo  = (const float*)d_in[9];
  const float* wg  = (const float*)d_in[10];
  const float* wu  = (const float*)d_in[11];
  const float* wd  = (const float*)d_in[12];
  const float* ln1 = (const float*)d_in[13];
  const float* ln2 = (const float*)d_in[14];
  const float* nw  = (const float*)d_in[15];
  float* h = (float*)d_out;

  // ws layout (u16 elems): W 67.1M | xbf 8.4M | qkv 10.5M | vT 1.05M | attno 8.4M | gate 67.1M
  u16* W     = (u16*)d_ws;
  u16* xbf   = W + 67108864ull;
  u16* qkv   = xbf + 8388608ull;
  u16* vTb   = qkv + 10485760ull;
  u16* attno = vTb + 1048576ull;
  u16* gateb = attno + 8388608ull;
  float* pbuf = (float*)(W + 33554432ull);  // split-K partials (2 x 8.4M f32)

  hipFuncSetAttribute(reinterpret_cast<const void*>(gemm8p<0>), hipFuncAttributeMaxDynamicSharedMemorySize, 131072);
  hipFuncSetAttribute(reinterpret_cast<const void*>(gemm8p<2>), hipFuncAttributeMaxDynamicSharedMemorySize, 131072);
  hipFuncSetAttribute(reinterpret_cast<const void*>(gemm8p<3>), hipFuncAttributeMaxDynamicSharedMemorySize, 131072);
  hipFuncSetAttribute(reinterpret_cast<const void*>(flash_kernel), hipFuncAttributeMaxDynamicSharedMemorySize, 70656);

  hipMemcpyAsync(h, hidden, sizeof(float) * 8388608ull, hipMemcpyDeviceToDevice, stream);

  auto cvt = [&](const float* src, u16* dst, long n) {
    int n4 = (int)(n >> 2);
    int blocks = (n4 + 255) / 256;
    if (blocks > 2048) blocks = 2048;
    cvt_kernel<<<blocks, 256, 0, stream>>>(src, dst, n4);
  };

  for (int l = 0; l < 2; ++l) {
    const float* lwq = wq + (size_t)l * 2048 * 2048;
    const float* lwk = wk + (size_t)l * 256 * 2048;
    const float* lwv = wv + (size_t)l * 256 * 2048;
    const float* lwo = wo + (size_t)l * 2048 * 2048;
    const float* lwg = wg + (size_t)l * 16384 * 2048;
    const float* lwu = wu + (size_t)l * 16384 * 2048;
    const float* lwd = wd + (size_t)l * 2048 * 16384;

    // x = rms(h, ln1)
    rms_kernel<true><<<4096, 256, 0, stream>>>(h, ln1 + l * 2048, xbf, nullptr);

    // fused qkv projection
    cvt(lwq, W, 4194304);
    cvt(lwk, W + 4194304, 524288);
    cvt(lwv, W + 4718592, 524288);
    gemm128<0><<<dim3(32 * 20, 1, 1), 256, 0, stream>>>(xbf, W, qkv, nullptr,
                                                        4096, 2560, 2048, 2048, 2048, 2560);

    rope_kernel<<<dim3(2048, 2), 256, 0, stream>>>(qkv, cosT, sinT);
    vtrans_kernel<<<dim3(32, 4, 2), 256, 0, stream>>>(qkv, vTb);
    flash_kernel<<<dim3(32, 8, 2), 256, 70656, stream>>>(qkv, vTb, attno);

    // h += attn_out @ wo^T   (split-K x2 -> partials -> combine)
    cvt(lwo, W, 4194304);
    gemm128<3><<<dim3(32 * 16, 1, 2), 256, 0, stream>>>(attno, W, nullptr, pbuf,
                                                        4096, 2048, 1024, 2048, 2048, 2048);
    combine_kernel<<<2048, 256, 0, stream>>>(h, pbuf, pbuf + 8388608ull, 2097152);

    // x = rms(h, ln2)
    rms_kernel<true><<<4096, 256, 0, stream>>>(h, ln2 + l * 2048, xbf, nullptr);

    // gate = x @ wg^T (8-phase v3); prod = gelu(gate) * (x @ wu^T) in place
    cvt(lwg, W, 33554432);
    cvt(lwu, W + 33554432, 33554432);
    gemm8p<0><<<dim3(1024, 1, 1), 512, 131072, stream>>>(xbf, W, gateb, nullptr,
                                                         4096, 16384, 2048, 2048, 2048, 16384);
    gemm8p<2><<<dim3(1024, 1, 1), 512, 131072, stream>>>(xbf, W + 33554432, gateb, nullptr,
                                                         4096, 16384, 2048, 2048, 2048, 16384);

    // h += prod @ wd^T  (8-phase v3, split-K x2 -> partials -> combine)
    cvt(lwd, W, 33554432);
    gemm8p<3><<<dim3(128, 1, 2), 512, 131072, stream>>>(gateb, W, nullptr, pbuf,
                                                        4096, 2048, 8192, 16384, 16384, 2048);
    combine_kernel<<<2048, 256, 0, stream>>>(h, pbuf, pbuf + 8388608ull, 2097152);
  }

  // final norm (in place, f32 out)
  rms_kernel<false><<<4096, 256, 0, stream>>>(h, nw, nullptr, h);
}

// Round 13
// 2610.474 us; speedup vs baseline: 1.0168x; 1.0168x over previous
//
#include <hip/hip_runtime.h>
#include <cstdint>
#include <cstddef>

// ---------------------------------------------------------------------------
// Gemma 2-layer forward, MI355X. Round 13: consolidation of best-measured
//   per-op kernels: fused gate+up gemm128gu (round 7, 838 TF) + gemm8p v2
//   down-proj (round 10/11) + gemm128 qkv/o-proj + round-11 staged flash.
// ---------------------------------------------------------------------------

typedef unsigned short u16;
typedef __bf16 bf16x8 __attribute__((ext_vector_type(8)));
typedef float f32x4 __attribute__((ext_vector_type(4)));

#define S_LEN 2048
#define HDIM  2048
#define QKV_N 2560
#define HD    256
#define ATT_SCALE 0.0625f

__device__ __forceinline__ u16 f2b(float f) {
  union { float f; unsigned u; } x; x.f = f;
  unsigned r = x.u + 0x7FFFu + ((x.u >> 16) & 1u);
  return (u16)(r >> 16);
}
__device__ __forceinline__ float b2f(u16 b) {
  union { unsigned u; float f; } x; x.u = ((unsigned)b) << 16;
  return x.f;
}

typedef __attribute__((address_space(1))) void as1_void;
typedef __attribute__((address_space(3))) void as3_void;
__device__ __forceinline__ void gload_lds16(const void* g, void* l) {
  __builtin_amdgcn_global_load_lds((as1_void*)((void*)g), (as3_void*)l, 16, 0, 0);
}

__device__ __forceinline__ void barrier_raw() {
  __builtin_amdgcn_sched_barrier(0);
  asm volatile("" ::: "memory");
  __builtin_amdgcn_s_barrier();
  asm volatile("" ::: "memory");
  __builtin_amdgcn_sched_barrier(0);
}

__device__ __forceinline__ float gelu_tanh(float x) {
  float t = tanhf(0.7978845608028654f * (x + 0.044715f * x * x * x));
  return 0.5f * x * (1.0f + t);
}

// ---------------------------------------------------------------------------
__global__ void cvt_kernel(const float* __restrict__ in, u16* __restrict__ out, int n4) {
  int idx = blockIdx.x * blockDim.x + threadIdx.x;
  int stride = gridDim.x * blockDim.x;
  for (int i = idx; i < n4; i += stride) {
    f32x4 v = reinterpret_cast<const f32x4*>(in)[i];
    unsigned lo = (unsigned)f2b(v[0]) | ((unsigned)f2b(v[1]) << 16);
    unsigned hi = (unsigned)f2b(v[2]) | ((unsigned)f2b(v[3]) << 16);
    uint2 p; p.x = lo; p.y = hi;
    reinterpret_cast<uint2*>(out)[i] = p;
  }
}

// ---------------------------------------------------------------------------
template<bool OBF>
__launch_bounds__(256)
__global__ void rms_kernel(const float* in, const float* w, u16* obf, float* of) {
  const int row = blockIdx.x;
  const int tid = threadIdx.x;
  const float* x = in + (size_t)row * HDIM;
  f32x4 v0 = reinterpret_cast<const f32x4*>(x)[tid];
  f32x4 v1 = reinterpret_cast<const f32x4*>(x)[tid + 256];
  float ss = v0[0]*v0[0] + v0[1]*v0[1] + v0[2]*v0[2] + v0[3]*v0[3]
           + v1[0]*v1[0] + v1[1]*v1[1] + v1[2]*v1[2] + v1[3]*v1[3];
#pragma unroll
  for (int off = 32; off > 0; off >>= 1) ss += __shfl_xor(ss, off);
  __shared__ float sred[4];
  if ((tid & 63) == 0) sred[tid >> 6] = ss;
  __syncthreads();
  float tot = sred[0] + sred[1] + sred[2] + sred[3];
  float r = rsqrtf(tot * (1.0f / (float)HDIM) + 1e-6f);
  f32x4 w0 = reinterpret_cast<const f32x4*>(w)[tid];
  f32x4 w1 = reinterpret_cast<const f32x4*>(w)[tid + 256];
#pragma unroll
  for (int j = 0; j < 4; ++j) {
    float a = v0[j] * r * (1.0f + w0[j]);
    float b = v1[j] * r * (1.0f + w1[j]);
    if (OBF) {
      obf[(size_t)row * HDIM + tid * 4 + j]        = f2b(a);
      obf[(size_t)row * HDIM + 1024 + tid * 4 + j] = f2b(b);
    } else {
      of[(size_t)row * HDIM + tid * 4 + j]        = a;
      of[(size_t)row * HDIM + 1024 + tid * 4 + j] = b;
    }
  }
}

// ---------------------------------------------------------------------------
// gemm128 (m97 replica): qkv + o-proj. EPI 0: Cb=bf16  3: split-K partial
// ---------------------------------------------------------------------------
template<int EPI>
__launch_bounds__(256, 4)
__global__ void gemm128(const u16* __restrict__ A, const u16* __restrict__ B,
                        u16* Cb, float* Cf, int M, int N, int K,
                        int lda, int ldb, int ldc) {
  __shared__ alignas(16) u16 As[128 * 64];
  __shared__ alignas(16) u16 Bs[128 * 64];
  const int tid = threadIdx.x;
  const int lane = tid & 63, w = tid >> 6;
  const int l16 = lane & 15, lhi = lane >> 4;
  const int wr = w >> 1, wc = w & 1;

  const int nwg = gridDim.x, bid = blockIdx.x;
  const int q = nwg >> 3, rm = nwg & 7, xc = bid & 7, li = bid >> 3;
  const int swz = (xc < rm ? xc * (q + 1) : rm * (q + 1) + (xc - rm) * q) + li;
  const int MT = M >> 7;
  const int m0 = (swz % MT) << 7;
  const int n0 = (swz / MT) << 7;
  const int kbase = blockIdx.z * K;

  const u16 *sA[4], *sB[4];
#pragma unroll
  for (int c = 0; c < 4; ++c) {
    int o = c * 4096 + w * 1024 + lane * 16;
    int r = o >> 7, s = (o >> 4) & 7;
    int ks = (s ^ (r & 7)) << 3;
    sA[c] = A + (size_t)(m0 + r) * lda + kbase + ks;
    sB[c] = B + (size_t)(n0 + r) * ldb + kbase + ks;
  }

  int aoff[2][4], boff[2][4];
#pragma unroll
  for (int kf = 0; kf < 2; ++kf)
#pragma unroll
    for (int f = 0; f < 4; ++f) {
      int ra = wr * 64 + f * 16 + l16;
      int rb = wc * 64 + f * 16 + l16;
      int sl = ((kf * 4 + lhi) ^ (l16 & 7)) << 4;
      aoff[kf][f] = ra * 128 + sl;
      boff[kf][f] = rb * 128 + sl;
    }

  f32x4 acc[4][4] = {};
  const char* pa = (const char*)As;
  const char* pb = (const char*)Bs;

  for (int k0 = 0; k0 < K; k0 += 64) {
#pragma unroll
    for (int c = 0; c < 4; ++c)
      gload_lds16(sA[c] + k0, (char*)As + c * 4096 + w * 1024);
#pragma unroll
    for (int c = 0; c < 4; ++c)
      gload_lds16(sB[c] + k0, (char*)Bs + c * 4096 + w * 1024);
    __syncthreads();
#pragma unroll
    for (int kf = 0; kf < 2; ++kf) {
      bf16x8 af[4], bf[4];
#pragma unroll
      for (int f = 0; f < 4; ++f) af[f] = *reinterpret_cast<const bf16x8*>(pa + aoff[kf][f]);
#pragma unroll
      for (int f = 0; f < 4; ++f) bf[f] = *reinterpret_cast<const bf16x8*>(pb + boff[kf][f]);
#pragma unroll
      for (int mf = 0; mf < 4; ++mf)
#pragma unroll
        for (int nf = 0; nf < 4; ++nf)
          acc[mf][nf] = __builtin_amdgcn_mfma_f32_16x16x32_bf16(af[mf], bf[nf], acc[mf][nf], 0, 0, 0);
    }
    __syncthreads();
  }

#pragma unroll
  for (int mf = 0; mf < 4; ++mf)
#pragma unroll
    for (int nf = 0; nf < 4; ++nf)
#pragma unroll
      for (int rr = 0; rr < 4; ++rr) {
        int row = m0 + wr * 64 + mf * 16 + lhi * 4 + rr;
        int col = n0 + wc * 64 + nf * 16 + l16;
        size_t idx = (size_t)row * ldc + col;
        float v = acc[mf][nf][rr];
        if (EPI == 0) Cb[idx] = f2b(v);
        else          Cf[(size_t)blockIdx.z * ((size_t)M * N) + idx] = v;
      }
}

// ---------------------------------------------------------------------------
// Fused gate+up GEMM (round-7 proven, 838 TF): prod = gelu(A@Bg^T)*(A@Bu^T).
// Shared A tile, two B panels, dual accumulators. 48 KB LDS, (256,2).
// ---------------------------------------------------------------------------
__launch_bounds__(256, 2)
__global__ void gemm128gu(const u16* __restrict__ A, const u16* __restrict__ Bg,
                          const u16* __restrict__ Bu, u16* __restrict__ Cb,
                          int M, int N, int K, int lda, int ldb, int ldc) {
  __shared__ alignas(16) u16 As[128 * 64];
  __shared__ alignas(16) u16 Gs[128 * 64];
  __shared__ alignas(16) u16 Us[128 * 64];
  const int tid = threadIdx.x;
  const int lane = tid & 63, w = tid >> 6;
  const int l16 = lane & 15, lhi = lane >> 4;
  const int wr = w >> 1, wc = w & 1;

  const int nwg = gridDim.x, bid = blockIdx.x;
  const int q = nwg >> 3, rm = nwg & 7, xc = bid & 7, li = bid >> 3;
  const int swz = (xc < rm ? xc * (q + 1) : rm * (q + 1) + (xc - rm) * q) + li;
  const int MT = M >> 7;
  const int m0 = (swz % MT) << 7;
  const int n0 = (swz / MT) << 7;

  const u16 *sA[4], *sG[4], *sU[4];
#pragma unroll
  for (int c = 0; c < 4; ++c) {
    int o = c * 4096 + w * 1024 + lane * 16;
    int r = o >> 7, s = (o >> 4) & 7;
    int ks = (s ^ (r & 7)) << 3;
    sA[c] = A  + (size_t)(m0 + r) * lda + ks;
    sG[c] = Bg + (size_t)(n0 + r) * ldb + ks;
    sU[c] = Bu + (size_t)(n0 + r) * ldb + ks;
  }

  int aoff[2][4], boff[2][4];
#pragma unroll
  for (int kf = 0; kf < 2; ++kf)
#pragma unroll
    for (int f = 0; f < 4; ++f) {
      int ra = wr * 64 + f * 16 + l16;
      int rb = wc * 64 + f * 16 + l16;
      int sl = ((kf * 4 + lhi) ^ (l16 & 7)) << 4;
      aoff[kf][f] = ra * 128 + sl;
      boff[kf][f] = rb * 128 + sl;
    }

  f32x4 accG[4][4] = {};
  f32x4 accU[4][4] = {};
  const char* pa = (const char*)As;
  const char* pg = (const char*)Gs;
  const char* pu = (const char*)Us;

  for (int k0 = 0; k0 < K; k0 += 64) {
#pragma unroll
    for (int c = 0; c < 4; ++c)
      gload_lds16(sA[c] + k0, (char*)As + c * 4096 + w * 1024);
#pragma unroll
    for (int c = 0; c < 4; ++c)
      gload_lds16(sG[c] + k0, (char*)Gs + c * 4096 + w * 1024);
#pragma unroll
    for (int c = 0; c < 4; ++c)
      gload_lds16(sU[c] + k0, (char*)Us + c * 4096 + w * 1024);
    __syncthreads();
#pragma unroll
    for (int kf = 0; kf < 2; ++kf) {
      bf16x8 af[4], bf[4];
#pragma unroll
      for (int f = 0; f < 4; ++f) af[f] = *reinterpret_cast<const bf16x8*>(pa + aoff[kf][f]);
#pragma unroll
      for (int f = 0; f < 4; ++f) bf[f] = *reinterpret_cast<const bf16x8*>(pg + boff[kf][f]);
#pragma unroll
      for (int mf = 0; mf < 4; ++mf)
#pragma unroll
        for (int nf = 0; nf < 4; ++nf)
          accG[mf][nf] = __builtin_amdgcn_mfma_f32_16x16x32_bf16(af[mf], bf[nf], accG[mf][nf], 0, 0, 0);
#pragma unroll
      for (int f = 0; f < 4; ++f) bf[f] = *reinterpret_cast<const bf16x8*>(pu + boff[kf][f]);
#pragma unroll
      for (int mf = 0; mf < 4; ++mf)
#pragma unroll
        for (int nf = 0; nf < 4; ++nf)
          accU[mf][nf] = __builtin_amdgcn_mfma_f32_16x16x32_bf16(af[mf], bf[nf], accU[mf][nf], 0, 0, 0);
    }
    __syncthreads();
  }

#pragma unroll
  for (int mf = 0; mf < 4; ++mf)
#pragma unroll
    for (int nf = 0; nf < 4; ++nf)
#pragma unroll
      for (int rr = 0; rr < 4; ++rr) {
        int row = m0 + wr * 64 + mf * 16 + lhi * 4 + rr;
        int col = n0 + wc * 64 + nf * 16 + l16;
        size_t idx = (size_t)row * ldc + col;
        Cb[idx] = f2b(gelu_tanh(accG[mf][nf][rr]) * accU[mf][nf][rr]);
      }
}

// ---------------------------------------------------------------------------
// gemm8p v2 — 8-phase 256^2 (round-10 proven): down-proj.
// ---------------------------------------------------------------------------
#define VMW(N) asm volatile("s_waitcnt vmcnt(" #N ")" ::: "memory")

#define STAGE_A(T, U)                                                         \
  { char* d_ = smem + (((size_t)((T) & 1)) << 16) + (U) * 16384 + w * 1024;   \
    const u16* s_ = pA + (size_t)(T) * 64 + (U) * A128;                       \
    gload_lds16(s_, d_); gload_lds16(s_ + A64, d_ + 8192); }

#define STAGE_B(T, KH)                                                        \
  { char* d_ = smem + (((size_t)((T) & 1)) << 16) + 32768 + (KH) * 16384 + w * 1024; \
    const u16* s_ = pB + (size_t)(T) * 64 + (KH) * 32;                        \
    gload_lds16(s_, d_); gload_lds16(s_ + B128, d_ + 8192); }

#define PHASE(KH, MH, FB, READB, STAGE_STMT, GATE_STMT)                       \
  {                                                                           \
    const char* va_ = cb + ((KH) ? pa1 : pa0) + (MH) * 16384;                 \
    bf16x8 fa0 = *reinterpret_cast<const bf16x8*>(va_);                       \
    bf16x8 fa1 = *reinterpret_cast<const bf16x8*>(va_ + 2048);                \
    bf16x8 fa2 = *reinterpret_cast<const bf16x8*>(va_ + 4096);                \
    bf16x8 fa3 = *reinterpret_cast<const bf16x8*>(va_ + 6144);                \
    if (READB) {                                                              \
      const char* vb_ = cb + qb + (KH) * 16384;                               \
      FB[0] = *reinterpret_cast<const bf16x8*>(vb_);                          \
      FB[1] = *reinterpret_cast<const bf16x8*>(vb_ + 1024);                   \
      FB[2] = *reinterpret_cast<const bf16x8*>(vb_ + 2048);                   \
      FB[3] = *reinterpret_cast<const bf16x8*>(vb_ + 3072);                   \
    }                                                                         \
    STAGE_STMT;                                                               \
    barrier_raw();                                                            \
    asm volatile("s_waitcnt lgkmcnt(0)" ::: "memory");                        \
    __builtin_amdgcn_sched_barrier(0);                                        \
    __builtin_amdgcn_s_setprio(1);                                            \
    _Pragma("unroll")                                                         \
    for (int nf = 0; nf < 4; ++nf) {                                          \
      acc[(MH)*4+0][nf] = __builtin_amdgcn_mfma_f32_16x16x32_bf16(fa0, FB[nf], acc[(MH)*4+0][nf], 0,0,0); \
      acc[(MH)*4+1][nf] = __builtin_amdgcn_mfma_f32_16x16x32_bf16(fa1, FB[nf], acc[(MH)*4+1][nf], 0,0,0); \
      acc[(MH)*4+2][nf] = __builtin_amdgcn_mfma_f32_16x16x32_bf16(fa2, FB[nf], acc[(MH)*4+2][nf], 0,0,0); \
      acc[(MH)*4+3][nf] = __builtin_amdgcn_mfma_f32_16x16x32_bf16(fa3, FB[nf], acc[(MH)*4+3][nf], 0,0,0); \
    }                                                                         \
    __builtin_amdgcn_s_setprio(0);                                            \
    GATE_STMT;                                                                \
    barrier_raw();                                                            \
  }

template<int EPI>
__launch_bounds__(512, 2)
__global__ void gemm8p(const u16* __restrict__ A, const u16* __restrict__ B,
                       u16* Cb, float* Cf, int M, int N, int Ks,
                       int lda, int ldb, int ldc) {
  extern __shared__ char smem[];   // 2 x 64KB
  const int tid = threadIdx.x;
  const int lane = tid & 63, w = tid >> 6;
  const int l16 = lane & 15, lhi = lane >> 4;
  const int wr = w >> 2, wc = w & 3;

  const int nwg = gridDim.x, bid = blockIdx.x;
  const int q = nwg >> 3, rm = nwg & 7, xc = bid & 7, li = bid >> 3;
  const int swz = (xc < rm ? xc * (q + 1) : rm * (q + 1) + (xc - rm) * q) + li;
  const int MT = M >> 8;
  const int m0 = (swz % MT) << 8;
  const int n0 = (swz / MT) << 8;
  const int kbase = blockIdx.z * Ks;
  const int NT = Ks >> 6;

  const size_t A64  = (size_t)lda * 64;
  const size_t A128 = (size_t)lda * 128;
  const size_t B128 = (size_t)ldb * 128;

  const u16 *pA, *pB;
  {
    int o = w * 1024 + lane * 16;
    int rA = o >> 7, sA = (o >> 4) & 7;
    pA = A + (size_t)(m0 + rA) * lda + kbase + ((sA ^ (rA & 7)) << 3);
    int rB = o >> 6, sB = (o >> 4) & 3;
    pB = B + (size_t)(n0 + rB) * ldb + kbase + ((sB ^ ((rB >> 1) & 3)) << 3);
  }

  const int pa0 = wr * 8192 + l16 * 128 + ((lhi ^ (l16 & 7)) << 4);
  const int pa1 = wr * 8192 + l16 * 128 + (((4 + lhi) ^ (l16 & 7)) << 4);
  const int qb  = 32768 + wc * 4096 + l16 * 64 + ((lhi ^ ((l16 >> 1) & 3)) << 4);

  f32x4 acc[8][4] = {};
  bf16x8 fb0[4], fb1[4];

  STAGE_A(0, 0); STAGE_B(0, 0); STAGE_A(0, 1); STAGE_B(0, 1);
  VMW(4);
  barrier_raw();

  for (int t = 0; t < NT - 1; ++t) {
    const char* cb = smem + (((size_t)(t & 1)) << 16);
    const int tn = t + 1;
    PHASE(0, 0, fb0, true,  STAGE_A(tn, 0), VMW(4));
    PHASE(0, 1, fb0, false, STAGE_B(tn, 0), VMW(4));
    PHASE(1, 0, fb1, true,  STAGE_A(tn, 1), );
    PHASE(1, 1, fb1, false, STAGE_B(tn, 1), VMW(4));
  }
  {
    const char* cb = smem + (((size_t)((NT - 1) & 1)) << 16);
    PHASE(0, 0, fb0, true,  , VMW(2));
    PHASE(0, 1, fb0, false, , VMW(0));
    PHASE(1, 0, fb1, true,  , );
    PHASE(1, 1, fb1, false, , );
  }

#pragma unroll
  for (int mf = 0; mf < 8; ++mf)
#pragma unroll
    for (int nf = 0; nf < 4; ++nf)
#pragma unroll
      for (int rr = 0; rr < 4; ++rr) {
        int row = m0 + (mf >> 2) * 128 + wr * 64 + (mf & 3) * 16 + lhi * 4 + rr;
        int col = n0 + wc * 64 + nf * 16 + l16;
        size_t idx = (size_t)row * ldc + col;
        float v = acc[mf][nf][rr];
        if (EPI == 0)      Cb[idx] = f2b(v);
        else if (EPI == 2) { float g = b2f(Cb[idx]); Cb[idx] = f2b(gelu_tanh(g) * v); }
        else               Cf[(size_t)blockIdx.z * ((size_t)M * N) + idx] = v;
      }
}

// h += p0 + p1 (split-K combine)
__global__ void combine_kernel(float* __restrict__ h, const float* __restrict__ p0,
                               const float* __restrict__ p1, int n4) {
  int idx = blockIdx.x * blockDim.x + threadIdx.x;
  int stride = gridDim.x * blockDim.x;
  for (int i = idx; i < n4; i += stride) {
    f32x4 a = reinterpret_cast<f32x4*>(h)[i];
    f32x4 b = reinterpret_cast<const f32x4*>(p0)[i];
    f32x4 c = reinterpret_cast<const f32x4*>(p1)[i];
    a = a + b + c;
    reinterpret_cast<f32x4*>(h)[i] = a;
  }
}

// ---------------------------------------------------------------------------
__global__ void rope_kernel(u16* qkv, const float* __restrict__ cosT, const float* __restrict__ sinT) {
  const int s = blockIdx.x, b = blockIdx.y;
  const size_t base = (size_t)(b * S_LEN + s) * QKV_N;
  for (int i = threadIdx.x; i < 9 * 128; i += 256) {
    int hh = i >> 7, d = i & 127;
    size_t off = base + (hh < 8 ? hh * 256 : 2048) + d;
    float x1 = b2f(qkv[off]), x2 = b2f(qkv[off + 128]);
    float c = cosT[s * 128 + d], sn = sinT[s * 128 + d];
    qkv[off]       = f2b(x1 * c - x2 * sn);
    qkv[off + 128] = f2b(x1 * sn + x2 * c);
  }
}

// ---------------------------------------------------------------------------
__global__ void vtrans_kernel(const u16* __restrict__ qkv, u16* __restrict__ vT) {
  __shared__ u16 t[64][65];
  const int s0 = blockIdx.x * 64, d0 = blockIdx.y * 64, b = blockIdx.z;
  for (int i = threadIdx.x; i < 4096; i += 256) {
    int r = i >> 6, c = i & 63;
    t[r][c] = qkv[(size_t)(b * S_LEN + s0 + r) * QKV_N + 2304 + d0 + c];
  }
  __syncthreads();
  for (int i = threadIdx.x; i < 4096; i += 256) {
    int r = i >> 6, c = i & 63;
    vT[(size_t)(b * HD + d0 + r) * S_LEN + s0 + c] = t[c][r];
  }
}

// ---------------------------------------------------------------------------
// Flash attention (round-11 proven): LDS-staged K/V^T, KVBLK=32, prefetch-2.
// ---------------------------------------------------------------------------
__launch_bounds__(256)
__global__ void flash_kernel(const u16* __restrict__ qkv, const u16* __restrict__ vT,
                             u16* __restrict__ outp) {
  extern __shared__ char fsm[];
  const int qt = blockIdx.x, hh = blockIdx.y, b = blockIdx.z;
  const int tid = threadIdx.x, lane = tid & 63, w = tid >> 6;
  const int l16 = lane & 15, lhi = lane >> 4;

  const u16* srcK[4]; const u16* srcV[4];
#pragma unroll
  for (int c = 0; c < 4; ++c) {
    int o = c * 4096 + tid * 16;
    int rK = o >> 9, sK = (o >> 4) & 31;
    srcK[c] = qkv + (size_t)(b * S_LEN + rK) * QKV_N + HDIM + ((sK ^ (rK & 7)) << 3);
    int dV = o >> 6, sV = (o >> 4) & 3;
    srcV[c] = vT + (size_t)(b * HD + dV) * S_LEN + ((sV ^ ((dV >> 1) & 3)) << 3);
  }
  const size_t KSTEP = (size_t)32 * QKV_N;

  u16* plds = (u16*)(fsm + 65536) + w * 640;

  bf16x8 aq[8];
  {
    const u16* qp = qkv + (size_t)(b * S_LEN + qt * 64 + w * 16 + l16) * QKV_N + hh * HD + lhi * 8;
#pragma unroll
    for (int kf = 0; kf < 8; ++kf)
      aq[kf] = *reinterpret_cast<const bf16x8*>(qp + kf * 32);
  }

  f32x4 oacc[16] = {};
  float mrow[4] = {-1e30f, -1e30f, -1e30f, -1e30f};
  float lrow[4] = {0.f, 0.f, 0.f, 0.f};
  const int rowg0 = qt * 64 + w * 16 + lhi * 4;
  const int NT = 2 * (qt + 1);
  const int m7 = l16 & 7;
  const int vcol = (lhi ^ ((l16 >> 1) & 3)) << 4;

  auto stage = [&](int t) {
    char* kb = fsm + (t & 1) * 16384;
    char* vb = fsm + 32768 + (t & 1) * 16384;
#pragma unroll
    for (int c = 0; c < 4; ++c) {
      gload_lds16(srcK[c] + (size_t)t * KSTEP, kb + c * 4096 + w * 1024);
      gload_lds16(srcV[c] + t * 32,            vb + c * 4096 + w * 1024);
    }
  };

  stage(0);
  stage(1);
  VMW(8);
  barrier_raw();

  for (int t = 0; t < NT; ++t) {
    const char* kb = fsm + (t & 1) * 16384;
    const char* vb = fsm + 32768 + (t & 1) * 16384;
    const int j0 = t * 32;

    f32x4 sacc[2] = {};
#pragma unroll
    for (int nf = 0; nf < 2; ++nf) {
      const char* rowp = kb + (nf * 16 + l16) * 512;
#pragma unroll
      for (int kf = 0; kf < 8; ++kf) {
        bf16x8 bk = *reinterpret_cast<const bf16x8*>(rowp + ((((kf << 2) + lhi) ^ m7) << 4));
        sacc[nf] = __builtin_amdgcn_mfma_f32_16x16x32_bf16(aq[kf], bk, sacc[nf], 0, 0, 0);
      }
    }

    float sval[2][4];
    float tm[4] = {-1e30f, -1e30f, -1e30f, -1e30f};
#pragma unroll
    for (int nf = 0; nf < 2; ++nf) {
      int colg = j0 + nf * 16 + l16;
#pragma unroll
      for (int r = 0; r < 4; ++r) {
        float sv = sacc[nf][r] * ATT_SCALE;
        if (colg > rowg0 + r) sv = -1e30f;
        sval[nf][r] = sv;
        tm[r] = fmaxf(tm[r], sv);
      }
    }
#pragma unroll
    for (int off = 1; off < 16; off <<= 1)
#pragma unroll
      for (int r = 0; r < 4; ++r) tm[r] = fmaxf(tm[r], __shfl_xor(tm[r], off));

    float alpha[4], psum[4] = {0.f, 0.f, 0.f, 0.f};
#pragma unroll
    for (int r = 0; r < 4; ++r) {
      float mn = fmaxf(mrow[r], tm[r]);
      alpha[r] = __expf(mrow[r] - mn);
      mrow[r] = mn;
    }
#pragma unroll
    for (int nf = 0; nf < 2; ++nf)
#pragma unroll
      for (int r = 0; r < 4; ++r) {
        float p = __expf(sval[nf][r] - mrow[r]);
        psum[r] += p;
        plds[(lhi * 4 + r) * 40 + nf * 16 + l16] = f2b(p);
      }
#pragma unroll
    for (int off = 1; off < 16; off <<= 1)
#pragma unroll
      for (int r = 0; r < 4; ++r) psum[r] += __shfl_xor(psum[r], off);
#pragma unroll
    for (int r = 0; r < 4; ++r) lrow[r] = lrow[r] * alpha[r] + psum[r];
#pragma unroll
    for (int nf2 = 0; nf2 < 16; ++nf2)
#pragma unroll
      for (int r = 0; r < 4; ++r) oacc[nf2][r] *= alpha[r];

    {
      bf16x8 pa = *reinterpret_cast<const bf16x8*>((const char*)plds + l16 * 80 + lhi * 16);
#pragma unroll
      for (int nf2 = 0; nf2 < 16; ++nf2) {
        bf16x8 bv = *reinterpret_cast<const bf16x8*>(vb + (nf2 * 16 + l16) * 64 + vcol);
        oacc[nf2] = __builtin_amdgcn_mfma_f32_16x16x32_bf16(pa, bv, oacc[nf2], 0, 0, 0);
      }
    }

    if (t + 1 < NT) {
      barrier_raw();
      if (t + 2 < NT) {
        stage(t + 2);
        VMW(8);
      } else {
        VMW(0);
      }
      barrier_raw();
    }
  }

  float inv[4];
#pragma unroll
  for (int r = 0; r < 4; ++r) inv[r] = 1.0f / lrow[r];
#pragma unroll
  for (int nf2 = 0; nf2 < 16; ++nf2)
#pragma unroll
    for (int r = 0; r < 4; ++r) {
      size_t idx = (size_t)(b * S_LEN + rowg0 + r) * HDIM + hh * HD + nf2 * 16 + l16;
      outp[idx] = f2b(oacc[nf2][r] * inv[r]);
    }
}

// ---------------------------------------------------------------------------
extern "C" void kernel_launch(void* const* d_in, const int* in_sizes, int n_in,
                              void* d_out, int out_size, void* d_ws, size_t ws_size,
                              hipStream_t stream) {
  const float* hidden = (const float*)d_in[0];
  const float* cosT   = (const float*)d_in[1];
  const float* sinT   = (const float*)d_in[2];
  const float* wq  = (const float*)d_in[6];
  const float* wk  = (const float*)d_in[7];
  const float* wv  = (const float*)d_in[8];
  const float* wo  = (const float*)d_in[9];
  const float* wg  = (const float*)d_in[10];
  const float* wu  = (const float*)d_in[11];
  const float* wd  = (const float*)d_in[12];
  const float* ln1 = (const float*)d_in[13];
  const float* ln2 = (const float*)d_in[14];
  const float* nw  = (const float*)d_in[15];
  float* h = (float*)d_out;

  // ws layout (u16 elems): W 67.1M | xbf 8.4M | qkv 10.5M | vT 1.05M | attno 8.4M | gate 67.1M
  u16* W     = (u16*)d_ws;
  u16* xbf   = W + 67108864ull;
  u16* qkv   = xbf + 8388608ull;
  u16* vTb   = qkv + 10485760ull;
  u16* attno = vTb + 1048576ull;
  u16* gateb = attno + 8388608ull;
  float* pbuf = (float*)(W + 33554432ull);  // split-K partials (2 x 8.4M f32)

  hipFuncSetAttribute(reinterpret_cast<const void*>(gemm8p<3>), hipFuncAttributeMaxDynamicSharedMemorySize, 131072);
  hipFuncSetAttribute(reinterpret_cast<const void*>(flash_kernel), hipFuncAttributeMaxDynamicSharedMemorySize, 70656);

  hipMemcpyAsync(h, hidden, sizeof(float) * 8388608ull, hipMemcpyDeviceToDevice, stream);

  auto cvt = [&](const float* src, u16* dst, long n) {
    int n4 = (int)(n >> 2);
    int blocks = (n4 + 255) / 256;
    if (blocks > 2048) blocks = 2048;
    cvt_kernel<<<blocks, 256, 0, stream>>>(src, dst, n4);
  };

  for (int l = 0; l < 2; ++l) {
    const float* lwq = wq + (size_t)l * 2048 * 2048;
    const float* lwk = wk + (size_t)l * 256 * 2048;
    const float* lwv = wv + (size_t)l * 256 * 2048;
    const float* lwo = wo + (size_t)l * 2048 * 2048;
    const float* lwg = wg + (size_t)l * 16384 * 2048;
    const float* lwu = wu + (size_t)l * 16384 * 2048;
    const float* lwd = wd + (size_t)l * 2048 * 16384;

    // x = rms(h, ln1)
    rms_kernel<true><<<4096, 256, 0, stream>>>(h, ln1 + l * 2048, xbf, nullptr);

    // fused qkv projection
    cvt(lwq, W, 4194304);
    cvt(lwk, W + 4194304, 524288);
    cvt(lwv, W + 4718592, 524288);
    gemm128<0><<<dim3(32 * 20, 1, 1), 256, 0, stream>>>(xbf, W, qkv, nullptr,
                                                        4096, 2560, 2048, 2048, 2048, 2560);

    rope_kernel<<<dim3(2048, 2), 256, 0, stream>>>(qkv, cosT, sinT);
    vtrans_kernel<<<dim3(32, 4, 2), 256, 0, stream>>>(qkv, vTb);
    flash_kernel<<<dim3(32, 8, 2), 256, 70656, stream>>>(qkv, vTb, attno);

    // h += attn_out @ wo^T   (split-K x2 -> partials -> combine)
    cvt(lwo, W, 4194304);
    gemm128<3><<<dim3(32 * 16, 1, 2), 256, 0, stream>>>(attno, W, nullptr, pbuf,
                                                        4096, 2048, 1024, 2048, 2048, 2048);
    combine_kernel<<<2048, 256, 0, stream>>>(h, pbuf, pbuf + 8388608ull, 2097152);

    // x = rms(h, ln2)
    rms_kernel<true><<<4096, 256, 0, stream>>>(h, ln2 + l * 2048, xbf, nullptr);

    // prod = gelu(x @ wg^T) * (x @ wu^T)   (fused, one dispatch)
    cvt(lwg, W, 33554432);
    cvt(lwu, W + 33554432, 33554432);
    gemm128gu<<<dim3(32 * 128, 1, 1), 256, 0, stream>>>(xbf, W, W + 33554432, gateb,
                                                        4096, 16384, 2048, 2048, 2048, 16384);

    // h += prod @ wd^T  (8-phase v2, split-K x2 -> partials -> combine)
    cvt(lwd, W, 33554432);
    gemm8p<3><<<dim3(128, 1, 2), 512, 131072, stream>>>(gateb, W, nullptr, pbuf,
                                                        4096, 2048, 8192, 16384, 16384, 2048);
    combine_kernel<<<2048, 256, 0, stream>>>(h, pbuf, pbuf + 8388608ull, 2097152);
  }

  // final norm (in place, f32 out)
  rms_kernel<false><<<4096, 256, 0, stream>>>(h, nw, nullptr, h);
}

// Round 14
// 2422.331 us; speedup vs baseline: 1.0958x; 1.0777x over previous
//
#include <hip/hip_runtime.h>
#include <cstdint>
#include <cstddef>

// ---------------------------------------------------------------------------
// Gemma 2-layer forward, MI355X. Round 14:
//   (1) down-proj -> gemm128 split-K x2 (4 blocks/CU; gemm8p retired),
//   (2) grouped 8x8 super-tile map in gemm128/gemm128gu (A-panel L2 reuse;
//       FETCH 727MB -> ~450MB predicted on gate/up).
//   Flash, rms, rope, vtrans, qkv unchanged (round-11/13 proven).
// ---------------------------------------------------------------------------

typedef unsigned short u16;
typedef __bf16 bf16x8 __attribute__((ext_vector_type(8)));
typedef float f32x4 __attribute__((ext_vector_type(4)));

#define S_LEN 2048
#define HDIM  2048
#define QKV_N 2560
#define HD    256
#define ATT_SCALE 0.0625f

__device__ __forceinline__ u16 f2b(float f) {
  union { float f; unsigned u; } x; x.f = f;
  unsigned r = x.u + 0x7FFFu + ((x.u >> 16) & 1u);
  return (u16)(r >> 16);
}
__device__ __forceinline__ float b2f(u16 b) {
  union { unsigned u; float f; } x; x.u = ((unsigned)b) << 16;
  return x.f;
}

typedef __attribute__((address_space(1))) void as1_void;
typedef __attribute__((address_space(3))) void as3_void;
__device__ __forceinline__ void gload_lds16(const void* g, void* l) {
  __builtin_amdgcn_global_load_lds((as1_void*)((void*)g), (as3_void*)l, 16, 0, 0);
}

__device__ __forceinline__ void barrier_raw() {
  __builtin_amdgcn_sched_barrier(0);
  asm volatile("" ::: "memory");
  __builtin_amdgcn_s_barrier();
  asm volatile("" ::: "memory");
  __builtin_amdgcn_sched_barrier(0);
}

__device__ __forceinline__ float gelu_tanh(float x) {
  float t = tanhf(0.7978845608028654f * (x + 0.044715f * x * x * x));
  return 0.5f * x * (1.0f + t);
}

// tile map: bijective XCD swizzle + (grouped 8x8 supertiles when divisible,
// else column-major). Returns m_tile, n_tile.
__device__ __forceinline__ void tile_map(int bid, int nwg, int MT, int& mt, int& nt) {
  const int q = nwg >> 3, rm = nwg & 7, xc = bid & 7, li = bid >> 3;
  const int swz = (xc < rm ? xc * (q + 1) : rm * (q + 1) + (xc - rm) * q) + li;
  const int NTt = nwg / MT;
  if ((MT & 7) == 0 && (NTt & 7) == 0) {
    const int ngm = MT >> 3;
    const int g = swz >> 6, w = swz & 63;
    const int gr = g % ngm, gc = g / ngm;
    mt = gr * 8 + (w & 7);
    nt = gc * 8 + (w >> 3);
  } else {
    mt = swz % MT;
    nt = swz / MT;
  }
}

// ---------------------------------------------------------------------------
__global__ void cvt_kernel(const float* __restrict__ in, u16* __restrict__ out, int n4) {
  int idx = blockIdx.x * blockDim.x + threadIdx.x;
  int stride = gridDim.x * blockDim.x;
  for (int i = idx; i < n4; i += stride) {
    f32x4 v = reinterpret_cast<const f32x4*>(in)[i];
    unsigned lo = (unsigned)f2b(v[0]) | ((unsigned)f2b(v[1]) << 16);
    unsigned hi = (unsigned)f2b(v[2]) | ((unsigned)f2b(v[3]) << 16);
    uint2 p; p.x = lo; p.y = hi;
    reinterpret_cast<uint2*>(out)[i] = p;
  }
}

// ---------------------------------------------------------------------------
template<bool OBF>
__launch_bounds__(256)
__global__ void rms_kernel(const float* in, const float* w, u16* obf, float* of) {
  const int row = blockIdx.x;
  const int tid = threadIdx.x;
  const float* x = in + (size_t)row * HDIM;
  f32x4 v0 = reinterpret_cast<const f32x4*>(x)[tid];
  f32x4 v1 = reinterpret_cast<const f32x4*>(x)[tid + 256];
  float ss = v0[0]*v0[0] + v0[1]*v0[1] + v0[2]*v0[2] + v0[3]*v0[3]
           + v1[0]*v1[0] + v1[1]*v1[1] + v1[2]*v1[2] + v1[3]*v1[3];
#pragma unroll
  for (int off = 32; off > 0; off >>= 1) ss += __shfl_xor(ss, off);
  __shared__ float sred[4];
  if ((tid & 63) == 0) sred[tid >> 6] = ss;
  __syncthreads();
  float tot = sred[0] + sred[1] + sred[2] + sred[3];
  float r = rsqrtf(tot * (1.0f / (float)HDIM) + 1e-6f);
  f32x4 w0 = reinterpret_cast<const f32x4*>(w)[tid];
  f32x4 w1 = reinterpret_cast<const f32x4*>(w)[tid + 256];
#pragma unroll
  for (int j = 0; j < 4; ++j) {
    float a = v0[j] * r * (1.0f + w0[j]);
    float b = v1[j] * r * (1.0f + w1[j]);
    if (OBF) {
      obf[(size_t)row * HDIM + tid * 4 + j]        = f2b(a);
      obf[(size_t)row * HDIM + 1024 + tid * 4 + j] = f2b(b);
    } else {
      of[(size_t)row * HDIM + tid * 4 + j]        = a;
      of[(size_t)row * HDIM + 1024 + tid * 4 + j] = b;
    }
  }
}

// ---------------------------------------------------------------------------
// gemm128 (m97 replica, (256,4) proven): qkv + o-proj + down-proj.
// EPI 0: Cb=bf16   3: Cf[z*M*N+idx]=acc (split-K partial)
// ---------------------------------------------------------------------------
template<int EPI>
__launch_bounds__(256, 4)
__global__ void gemm128(const u16* __restrict__ A, const u16* __restrict__ B,
                        u16* Cb, float* Cf, int M, int N, int K,
                        int lda, int ldb, int ldc) {
  __shared__ alignas(16) u16 As[128 * 64];
  __shared__ alignas(16) u16 Bs[128 * 64];
  const int tid = threadIdx.x;
  const int lane = tid & 63, w = tid >> 6;
  const int l16 = lane & 15, lhi = lane >> 4;
  const int wr = w >> 1, wc = w & 1;

  int mt, nt;
  tile_map(blockIdx.x, gridDim.x, M >> 7, mt, nt);
  const int m0 = mt << 7, n0 = nt << 7;
  const int kbase = blockIdx.z * K;

  const u16 *sA[4], *sB[4];
#pragma unroll
  for (int c = 0; c < 4; ++c) {
    int o = c * 4096 + w * 1024 + lane * 16;
    int r = o >> 7, s = (o >> 4) & 7;
    int ks = (s ^ (r & 7)) << 3;
    sA[c] = A + (size_t)(m0 + r) * lda + kbase + ks;
    sB[c] = B + (size_t)(n0 + r) * ldb + kbase + ks;
  }

  int aoff[2][4], boff[2][4];
#pragma unroll
  for (int kf = 0; kf < 2; ++kf)
#pragma unroll
    for (int f = 0; f < 4; ++f) {
      int ra = wr * 64 + f * 16 + l16;
      int rb = wc * 64 + f * 16 + l16;
      int sl = ((kf * 4 + lhi) ^ (l16 & 7)) << 4;
      aoff[kf][f] = ra * 128 + sl;
      boff[kf][f] = rb * 128 + sl;
    }

  f32x4 acc[4][4] = {};
  const char* pa = (const char*)As;
  const char* pb = (const char*)Bs;

  for (int k0 = 0; k0 < K; k0 += 64) {
#pragma unroll
    for (int c = 0; c < 4; ++c)
      gload_lds16(sA[c] + k0, (char*)As + c * 4096 + w * 1024);
#pragma unroll
    for (int c = 0; c < 4; ++c)
      gload_lds16(sB[c] + k0, (char*)Bs + c * 4096 + w * 1024);
    __syncthreads();
#pragma unroll
    for (int kf = 0; kf < 2; ++kf) {
      bf16x8 af[4], bf[4];
#pragma unroll
      for (int f = 0; f < 4; ++f) af[f] = *reinterpret_cast<const bf16x8*>(pa + aoff[kf][f]);
#pragma unroll
      for (int f = 0; f < 4; ++f) bf[f] = *reinterpret_cast<const bf16x8*>(pb + boff[kf][f]);
#pragma unroll
      for (int mf = 0; mf < 4; ++mf)
#pragma unroll
        for (int nf = 0; nf < 4; ++nf)
          acc[mf][nf] = __builtin_amdgcn_mfma_f32_16x16x32_bf16(af[mf], bf[nf], acc[mf][nf], 0, 0, 0);
    }
    __syncthreads();
  }

#pragma unroll
  for (int mf = 0; mf < 4; ++mf)
#pragma unroll
    for (int nf = 0; nf < 4; ++nf)
#pragma unroll
      for (int rr = 0; rr < 4; ++rr) {
        int row = m0 + wr * 64 + mf * 16 + lhi * 4 + rr;
        int col = n0 + wc * 64 + nf * 16 + l16;
        size_t idx = (size_t)row * ldc + col;
        float v = acc[mf][nf][rr];
        if (EPI == 0) Cb[idx] = f2b(v);
        else          Cf[(size_t)blockIdx.z * ((size_t)M * N) + idx] = v;
      }
}

// ---------------------------------------------------------------------------
// Fused gate+up GEMM (round-7 proven, + grouped tile map):
//   prod = gelu(A@Bg^T)*(A@Bu^T). 48 KB LDS, (256,2).
// ---------------------------------------------------------------------------
__launch_bounds__(256, 2)
__global__ void gemm128gu(const u16* __restrict__ A, const u16* __restrict__ Bg,
                          const u16* __restrict__ Bu, u16* __restrict__ Cb,
                          int M, int N, int K, int lda, int ldb, int ldc) {
  __shared__ alignas(16) u16 As[128 * 64];
  __shared__ alignas(16) u16 Gs[128 * 64];
  __shared__ alignas(16) u16 Us[128 * 64];
  const int tid = threadIdx.x;
  const int lane = tid & 63, w = tid >> 6;
  const int l16 = lane & 15, lhi = lane >> 4;
  const int wr = w >> 1, wc = w & 1;

  int mt, nt;
  tile_map(blockIdx.x, gridDim.x, M >> 7, mt, nt);
  const int m0 = mt << 7, n0 = nt << 7;

  const u16 *sA[4], *sG[4], *sU[4];
#pragma unroll
  for (int c = 0; c < 4; ++c) {
    int o = c * 4096 + w * 1024 + lane * 16;
    int r = o >> 7, s = (o >> 4) & 7;
    int ks = (s ^ (r & 7)) << 3;
    sA[c] = A  + (size_t)(m0 + r) * lda + ks;
    sG[c] = Bg + (size_t)(n0 + r) * ldb + ks;
    sU[c] = Bu + (size_t)(n0 + r) * ldb + ks;
  }

  int aoff[2][4], boff[2][4];
#pragma unroll
  for (int kf = 0; kf < 2; ++kf)
#pragma unroll
    for (int f = 0; f < 4; ++f) {
      int ra = wr * 64 + f * 16 + l16;
      int rb = wc * 64 + f * 16 + l16;
      int sl = ((kf * 4 + lhi) ^ (l16 & 7)) << 4;
      aoff[kf][f] = ra * 128 + sl;
      boff[kf][f] = rb * 128 + sl;
    }

  f32x4 accG[4][4] = {};
  f32x4 accU[4][4] = {};
  const char* pa = (const char*)As;
  const char* pg = (const char*)Gs;
  const char* pu = (const char*)Us;

  for (int k0 = 0; k0 < K; k0 += 64) {
#pragma unroll
    for (int c = 0; c < 4; ++c)
      gload_lds16(sA[c] + k0, (char*)As + c * 4096 + w * 1024);
#pragma unroll
    for (int c = 0; c < 4; ++c)
      gload_lds16(sG[c] + k0, (char*)Gs + c * 4096 + w * 1024);
#pragma unroll
    for (int c = 0; c < 4; ++c)
      gload_lds16(sU[c] + k0, (char*)Us + c * 4096 + w * 1024);
    __syncthreads();
#pragma unroll
    for (int kf = 0; kf < 2; ++kf) {
      bf16x8 af[4], bf[4];
#pragma unroll
      for (int f = 0; f < 4; ++f) af[f] = *reinterpret_cast<const bf16x8*>(pa + aoff[kf][f]);
#pragma unroll
      for (int f = 0; f < 4; ++f) bf[f] = *reinterpret_cast<const bf16x8*>(pg + boff[kf][f]);
#pragma unroll
      for (int mf = 0; mf < 4; ++mf)
#pragma unroll
        for (int nf = 0; nf < 4; ++nf)
          accG[mf][nf] = __builtin_amdgcn_mfma_f32_16x16x32_bf16(af[mf], bf[nf], accG[mf][nf], 0, 0, 0);
#pragma unroll
      for (int f = 0; f < 4; ++f) bf[f] = *reinterpret_cast<const bf16x8*>(pu + boff[kf][f]);
#pragma unroll
      for (int mf = 0; mf < 4; ++mf)
#pragma unroll
        for (int nf = 0; nf < 4; ++nf)
          accU[mf][nf] = __builtin_amdgcn_mfma_f32_16x16x32_bf16(af[mf], bf[nf], accU[mf][nf], 0, 0, 0);
    }
    __syncthreads();
  }

#pragma unroll
  for (int mf = 0; mf < 4; ++mf)
#pragma unroll
    for (int nf = 0; nf < 4; ++nf)
#pragma unroll
      for (int rr = 0; rr < 4; ++rr) {
        int row = m0 + wr * 64 + mf * 16 + lhi * 4 + rr;
        int col = n0 + wc * 64 + nf * 16 + l16;
        size_t idx = (size_t)row * ldc + col;
        Cb[idx] = f2b(gelu_tanh(accG[mf][nf][rr]) * accU[mf][nf][rr]);
      }
}

// h += p0 + p1 (split-K combine)
__global__ void combine_kernel(float* __restrict__ h, const float* __restrict__ p0,
                               const float* __restrict__ p1, int n4) {
  int idx = blockIdx.x * blockDim.x + threadIdx.x;
  int stride = gridDim.x * blockDim.x;
  for (int i = idx; i < n4; i += stride) {
    f32x4 a = reinterpret_cast<f32x4*>(h)[i];
    f32x4 b = reinterpret_cast<const f32x4*>(p0)[i];
    f32x4 c = reinterpret_cast<const f32x4*>(p1)[i];
    a = a + b + c;
    reinterpret_cast<f32x4*>(h)[i] = a;
  }
}

// ---------------------------------------------------------------------------
__global__ void rope_kernel(u16* qkv, const float* __restrict__ cosT, const float* __restrict__ sinT) {
  const int s = blockIdx.x, b = blockIdx.y;
  const size_t base = (size_t)(b * S_LEN + s) * QKV_N;
  for (int i = threadIdx.x; i < 9 * 128; i += 256) {
    int hh = i >> 7, d = i & 127;
    size_t off = base + (hh < 8 ? hh * 256 : 2048) + d;
    float x1 = b2f(qkv[off]), x2 = b2f(qkv[off + 128]);
    float c = cosT[s * 128 + d], sn = sinT[s * 128 + d];
    qkv[off]       = f2b(x1 * c - x2 * sn);
    qkv[off + 128] = f2b(x1 * sn + x2 * c);
  }
}

// ---------------------------------------------------------------------------
__global__ void vtrans_kernel(const u16* __restrict__ qkv, u16* __restrict__ vT) {
  __shared__ u16 t[64][65];
  const int s0 = blockIdx.x * 64, d0 = blockIdx.y * 64, b = blockIdx.z;
  for (int i = threadIdx.x; i < 4096; i += 256) {
    int r = i >> 6, c = i & 63;
    t[r][c] = qkv[(size_t)(b * S_LEN + s0 + r) * QKV_N + 2304 + d0 + c];
  }
  __syncthreads();
  for (int i = threadIdx.x; i < 4096; i += 256) {
    int r = i >> 6, c = i & 63;
    vT[(size_t)(b * HD + d0 + r) * S_LEN + s0 + c] = t[c][r];
  }
}

// ---------------------------------------------------------------------------
// Flash attention (round-11 proven): LDS-staged K/V^T, KVBLK=32, prefetch-2.
// ---------------------------------------------------------------------------
#define VMW(N) asm volatile("s_waitcnt vmcnt(" #N ")" ::: "memory")

__launch_bounds__(256)
__global__ void flash_kernel(const u16* __restrict__ qkv, const u16* __restrict__ vT,
                             u16* __restrict__ outp) {
  extern __shared__ char fsm[];
  const int qt = blockIdx.x, hh = blockIdx.y, b = blockIdx.z;
  const int tid = threadIdx.x, lane = tid & 63, w = tid >> 6;
  const int l16 = lane & 15, lhi = lane >> 4;

  const u16* srcK[4]; const u16* srcV[4];
#pragma unroll
  for (int c = 0; c < 4; ++c) {
    int o = c * 4096 + tid * 16;
    int rK = o >> 9, sK = (o >> 4) & 31;
    srcK[c] = qkv + (size_t)(b * S_LEN + rK) * QKV_N + HDIM + ((sK ^ (rK & 7)) << 3);
    int dV = o >> 6, sV = (o >> 4) & 3;
    srcV[c] = vT + (size_t)(b * HD + dV) * S_LEN + ((sV ^ ((dV >> 1) & 3)) << 3);
  }
  const size_t KSTEP = (size_t)32 * QKV_N;

  u16* plds = (u16*)(fsm + 65536) + w * 640;

  bf16x8 aq[8];
  {
    const u16* qp = qkv + (size_t)(b * S_LEN + qt * 64 + w * 16 + l16) * QKV_N + hh * HD + lhi * 8;
#pragma unroll
    for (int kf = 0; kf < 8; ++kf)
      aq[kf] = *reinterpret_cast<const bf16x8*>(qp + kf * 32);
  }

  f32x4 oacc[16] = {};
  float mrow[4] = {-1e30f, -1e30f, -1e30f, -1e30f};
  float lrow[4] = {0.f, 0.f, 0.f, 0.f};
  const int rowg0 = qt * 64 + w * 16 + lhi * 4;
  const int NT = 2 * (qt + 1);
  const int m7 = l16 & 7;
  const int vcol = (lhi ^ ((l16 >> 1) & 3)) << 4;

  auto stage = [&](int t) {
    char* kb = fsm + (t & 1) * 16384;
    char* vb = fsm + 32768 + (t & 1) * 16384;
#pragma unroll
    for (int c = 0; c < 4; ++c) {
      gload_lds16(srcK[c] + (size_t)t * KSTEP, kb + c * 4096 + w * 1024);
      gload_lds16(srcV[c] + t * 32,            vb + c * 4096 + w * 1024);
    }
  };

  stage(0);
  stage(1);
  VMW(8);
  barrier_raw();

  for (int t = 0; t < NT; ++t) {
    const char* kb = fsm + (t & 1) * 16384;
    const char* vb = fsm + 32768 + (t & 1) * 16384;
    const int j0 = t * 32;

    f32x4 sacc[2] = {};
#pragma unroll
    for (int nf = 0; nf < 2; ++nf) {
      const char* rowp = kb + (nf * 16 + l16) * 512;
#pragma unroll
      for (int kf = 0; kf < 8; ++kf) {
        bf16x8 bk = *reinterpret_cast<const bf16x8*>(rowp + ((((kf << 2) + lhi) ^ m7) << 4));
        sacc[nf] = __builtin_amdgcn_mfma_f32_16x16x32_bf16(aq[kf], bk, sacc[nf], 0, 0, 0);
      }
    }

    float sval[2][4];
    float tm[4] = {-1e30f, -1e30f, -1e30f, -1e30f};
#pragma unroll
    for (int nf = 0; nf < 2; ++nf) {
      int colg = j0 + nf * 16 + l16;
#pragma unroll
      for (int r = 0; r < 4; ++r) {
        float sv = sacc[nf][r] * ATT_SCALE;
        if (colg > rowg0 + r) sv = -1e30f;
        sval[nf][r] = sv;
        tm[r] = fmaxf(tm[r], sv);
      }
    }
#pragma unroll
    for (int off = 1; off < 16; off <<= 1)
#pragma unroll
      for (int r = 0; r < 4; ++r) tm[r] = fmaxf(tm[r], __shfl_xor(tm[r], off));

    float alpha[4], psum[4] = {0.f, 0.f, 0.f, 0.f};
#pragma unroll
    for (int r = 0; r < 4; ++r) {
      float mn = fmaxf(mrow[r], tm[r]);
      alpha[r] = __expf(mrow[r] - mn);
      mrow[r] = mn;
    }
#pragma unroll
    for (int nf = 0; nf < 2; ++nf)
#pragma unroll
      for (int r = 0; r < 4; ++r) {
        float p = __expf(sval[nf][r] - mrow[r]);
        psum[r] += p;
        plds[(lhi * 4 + r) * 40 + nf * 16 + l16] = f2b(p);
      }
#pragma unroll
    for (int off = 1; off < 16; off <<= 1)
#pragma unroll
      for (int r = 0; r < 4; ++r) psum[r] += __shfl_xor(psum[r], off);
#pragma unroll
    for (int r = 0; r < 4; ++r) lrow[r] = lrow[r] * alpha[r] + psum[r];
#pragma unroll
    for (int nf2 = 0; nf2 < 16; ++nf2)
#pragma unroll
      for (int r = 0; r < 4; ++r) oacc[nf2][r] *= alpha[r];

    {
      bf16x8 pa = *reinterpret_cast<const bf16x8*>((const char*)plds + l16 * 80 + lhi * 16);
#pragma unroll
      for (int nf2 = 0; nf2 < 16; ++nf2) {
        bf16x8 bv = *reinterpret_cast<const bf16x8*>(vb + (nf2 * 16 + l16) * 64 + vcol);
        oacc[nf2] = __builtin_amdgcn_mfma_f32_16x16x32_bf16(pa, bv, oacc[nf2], 0, 0, 0);
      }
    }

    if (t + 1 < NT) {
      barrier_raw();
      if (t + 2 < NT) {
        stage(t + 2);
        VMW(8);
      } else {
        VMW(0);
      }
      barrier_raw();
    }
  }

  float inv[4];
#pragma unroll
  for (int r = 0; r < 4; ++r) inv[r] = 1.0f / lrow[r];
#pragma unroll
  for (int nf2 = 0; nf2 < 16; ++nf2)
#pragma unroll
    for (int r = 0; r < 4; ++r) {
      size_t idx = (size_t)(b * S_LEN + rowg0 + r) * HDIM + hh * HD + nf2 * 16 + l16;
      outp[idx] = f2b(oacc[nf2][r] * inv[r]);
    }
}

// ---------------------------------------------------------------------------
extern "C" void kernel_launch(void* const* d_in, const int* in_sizes, int n_in,
                              void* d_out, int out_size, void* d_ws, size_t ws_size,
                              hipStream_t stream) {
  const float* hidden = (const float*)d_in[0];
  const float* cosT   = (const float*)d_in[1];
  const float* sinT   = (const float*)d_in[2];
  const float* wq  = (const float*)d_in[6];
  const float* wk  = (const float*)d_in[7];
  const float* wv  = (const float*)d_in[8];
  const float* wo  = (const float*)d_in[9];
  const float* wg  = (const float*)d_in[10];
  const float* wu  = (const float*)d_in[11];
  const float* wd  = (const float*)d_in[12];
  const float* ln1 = (const float*)d_in[13];
  const float* ln2 = (const float*)d_in[14];
  const float* nw  = (const float*)d_in[15];
  float* h = (float*)d_out;

  // ws layout (u16 elems): W 67.1M | xbf 8.4M | qkv 10.5M | vT 1.05M | attno 8.4M | gate 67.1M
  u16* W     = (u16*)d_ws;
  u16* xbf   = W + 67108864ull;
  u16* qkv   = xbf + 8388608ull;
  u16* vTb   = qkv + 10485760ull;
  u16* attno = vTb + 1048576ull;
  u16* gateb = attno + 8388608ull;
  float* pbuf = (float*)(W + 33554432ull);  // split-K partials (2 x 8.4M f32)

  hipFuncSetAttribute(reinterpret_cast<const void*>(flash_kernel), hipFuncAttributeMaxDynamicSharedMemorySize, 70656);

  hipMemcpyAsync(h, hidden, sizeof(float) * 8388608ull, hipMemcpyDeviceToDevice, stream);

  auto cvt = [&](const float* src, u16* dst, long n) {
    int n4 = (int)(n >> 2);
    int blocks = (n4 + 255) / 256;
    if (blocks > 2048) blocks = 2048;
    cvt_kernel<<<blocks, 256, 0, stream>>>(src, dst, n4);
  };

  for (int l = 0; l < 2; ++l) {
    const float* lwq = wq + (size_t)l * 2048 * 2048;
    const float* lwk = wk + (size_t)l * 256 * 2048;
    const float* lwv = wv + (size_t)l * 256 * 2048;
    const float* lwo = wo + (size_t)l * 2048 * 2048;
    const float* lwg = wg + (size_t)l * 16384 * 2048;
    const float* lwu = wu + (size_t)l * 16384 * 2048;
    const float* lwd = wd + (size_t)l * 2048 * 16384;

    // x = rms(h, ln1)
    rms_kernel<true><<<4096, 256, 0, stream>>>(h, ln1 + l * 2048, xbf, nullptr);

    // fused qkv projection (NT=20 -> column-major fallback map)
    cvt(lwq, W, 4194304);
    cvt(lwk, W + 4194304, 524288);
    cvt(lwv, W + 4718592, 524288);
    gemm128<0><<<dim3(32 * 20, 1, 1), 256, 0, stream>>>(xbf, W, qkv, nullptr,
                                                        4096, 2560, 2048, 2048, 2048, 2560);

    rope_kernel<<<dim3(2048, 2), 256, 0, stream>>>(qkv, cosT, sinT);
    vtrans_kernel<<<dim3(32, 4, 2), 256, 0, stream>>>(qkv, vTb);
    flash_kernel<<<dim3(32, 8, 2), 256, 70656, stream>>>(qkv, vTb, attno);

    // h += attn_out @ wo^T   (split-K x2, grouped map 32x16)
    cvt(lwo, W, 4194304);
    gemm128<3><<<dim3(32 * 16, 1, 2), 256, 0, stream>>>(attno, W, nullptr, pbuf,
                                                        4096, 2048, 1024, 2048, 2048, 2048);
    combine_kernel<<<2048, 256, 0, stream>>>(h, pbuf, pbuf + 8388608ull, 2097152);

    // x = rms(h, ln2)
    rms_kernel<true><<<4096, 256, 0, stream>>>(h, ln2 + l * 2048, xbf, nullptr);

    // prod = gelu(x @ wg^T) * (x @ wu^T)   (fused, grouped map 32x128)
    cvt(lwg, W, 33554432);
    cvt(lwu, W + 33554432, 33554432);
    gemm128gu<<<dim3(32 * 128, 1, 1), 256, 0, stream>>>(xbf, W, W + 33554432, gateb,
                                                        4096, 16384, 2048, 2048, 2048, 16384);

    // h += prod @ wd^T  (gemm128 split-K x2, 4 blocks/CU, grouped map 32x16)
    cvt(lwd, W, 33554432);
    gemm128<3><<<dim3(32 * 16, 1, 2), 256, 0, stream>>>(gateb, W, nullptr, pbuf,
                                                        4096, 2048, 8192, 16384, 16384, 2048);
    combine_kernel<<<2048, 256, 0, stream>>>(h, pbuf, pbuf + 8388608ull, 2097152);
  }

  // final norm (in place, f32 out)
  rms_kernel<false><<<4096, 256, 0, stream>>>(h, nw, nullptr, h);
}

// Round 15
// 2376.044 us; speedup vs baseline: 1.1171x; 1.0195x over previous
//
#include <hip/hip_runtime.h>
#include <cstdint>
#include <cstddef>

// ---------------------------------------------------------------------------
// Gemma 2-layer forward, MI355X. Round 15: down-proj + o-proj moved to new
//   gemm256n (BM=256 x BN=128, 4 waves of 128x64, 48 KB LDS, (256,2),
//   87.5 FLOP/staged-byte vs gemm128's 65) with split-K x2 + grouped map.
//   gu/qkv/flash unchanged (round-14 proven).
// ---------------------------------------------------------------------------

typedef unsigned short u16;
typedef __bf16 bf16x8 __attribute__((ext_vector_type(8)));
typedef float f32x4 __attribute__((ext_vector_type(4)));

#define S_LEN 2048
#define HDIM  2048
#define QKV_N 2560
#define HD    256
#define ATT_SCALE 0.0625f

__device__ __forceinline__ u16 f2b(float f) {
  union { float f; unsigned u; } x; x.f = f;
  unsigned r = x.u + 0x7FFFu + ((x.u >> 16) & 1u);
  return (u16)(r >> 16);
}
__device__ __forceinline__ float b2f(u16 b) {
  union { unsigned u; float f; } x; x.u = ((unsigned)b) << 16;
  return x.f;
}

typedef __attribute__((address_space(1))) void as1_void;
typedef __attribute__((address_space(3))) void as3_void;
__device__ __forceinline__ void gload_lds16(const void* g, void* l) {
  __builtin_amdgcn_global_load_lds((as1_void*)((void*)g), (as3_void*)l, 16, 0, 0);
}

__device__ __forceinline__ void barrier_raw() {
  __builtin_amdgcn_sched_barrier(0);
  asm volatile("" ::: "memory");
  __builtin_amdgcn_s_barrier();
  asm volatile("" ::: "memory");
  __builtin_amdgcn_sched_barrier(0);
}

__device__ __forceinline__ float gelu_tanh(float x) {
  float t = tanhf(0.7978845608028654f * (x + 0.044715f * x * x * x));
  return 0.5f * x * (1.0f + t);
}

// tile map: bijective XCD swizzle + grouped 8x8 supertiles when divisible.
__device__ __forceinline__ void tile_map(int bid, int nwg, int MT, int& mt, int& nt) {
  const int q = nwg >> 3, rm = nwg & 7, xc = bid & 7, li = bid >> 3;
  const int swz = (xc < rm ? xc * (q + 1) : rm * (q + 1) + (xc - rm) * q) + li;
  const int NTt = nwg / MT;
  if ((MT & 7) == 0 && (NTt & 7) == 0) {
    const int ngm = MT >> 3;
    const int g = swz >> 6, w = swz & 63;
    const int gr = g % ngm, gc = g / ngm;
    mt = gr * 8 + (w & 7);
    nt = gc * 8 + (w >> 3);
  } else {
    mt = swz % MT;
    nt = swz / MT;
  }
}

// ---------------------------------------------------------------------------
__global__ void cvt_kernel(const float* __restrict__ in, u16* __restrict__ out, int n4) {
  int idx = blockIdx.x * blockDim.x + threadIdx.x;
  int stride = gridDim.x * blockDim.x;
  for (int i = idx; i < n4; i += stride) {
    f32x4 v = reinterpret_cast<const f32x4*>(in)[i];
    unsigned lo = (unsigned)f2b(v[0]) | ((unsigned)f2b(v[1]) << 16);
    unsigned hi = (unsigned)f2b(v[2]) | ((unsigned)f2b(v[3]) << 16);
    uint2 p; p.x = lo; p.y = hi;
    reinterpret_cast<uint2*>(out)[i] = p;
  }
}

// ---------------------------------------------------------------------------
template<bool OBF>
__launch_bounds__(256)
__global__ void rms_kernel(const float* in, const float* w, u16* obf, float* of) {
  const int row = blockIdx.x;
  const int tid = threadIdx.x;
  const float* x = in + (size_t)row * HDIM;
  f32x4 v0 = reinterpret_cast<const f32x4*>(x)[tid];
  f32x4 v1 = reinterpret_cast<const f32x4*>(x)[tid + 256];
  float ss = v0[0]*v0[0] + v0[1]*v0[1] + v0[2]*v0[2] + v0[3]*v0[3]
           + v1[0]*v1[0] + v1[1]*v1[1] + v1[2]*v1[2] + v1[3]*v1[3];
#pragma unroll
  for (int off = 32; off > 0; off >>= 1) ss += __shfl_xor(ss, off);
  __shared__ float sred[4];
  if ((tid & 63) == 0) sred[tid >> 6] = ss;
  __syncthreads();
  float tot = sred[0] + sred[1] + sred[2] + sred[3];
  float r = rsqrtf(tot * (1.0f / (float)HDIM) + 1e-6f);
  f32x4 w0 = reinterpret_cast<const f32x4*>(w)[tid];
  f32x4 w1 = reinterpret_cast<const f32x4*>(w)[tid + 256];
#pragma unroll
  for (int j = 0; j < 4; ++j) {
    float a = v0[j] * r * (1.0f + w0[j]);
    float b = v1[j] * r * (1.0f + w1[j]);
    if (OBF) {
      obf[(size_t)row * HDIM + tid * 4 + j]        = f2b(a);
      obf[(size_t)row * HDIM + 1024 + tid * 4 + j] = f2b(b);
    } else {
      of[(size_t)row * HDIM + tid * 4 + j]        = a;
      of[(size_t)row * HDIM + 1024 + tid * 4 + j] = b;
    }
  }
}

// ---------------------------------------------------------------------------
// gemm128 (m97 replica, (256,4)): qkv projection.
// ---------------------------------------------------------------------------
template<int EPI>
__launch_bounds__(256, 4)
__global__ void gemm128(const u16* __restrict__ A, const u16* __restrict__ B,
                        u16* Cb, float* Cf, int M, int N, int K,
                        int lda, int ldb, int ldc) {
  __shared__ alignas(16) u16 As[128 * 64];
  __shared__ alignas(16) u16 Bs[128 * 64];
  const int tid = threadIdx.x;
  const int lane = tid & 63, w = tid >> 6;
  const int l16 = lane & 15, lhi = lane >> 4;
  const int wr = w >> 1, wc = w & 1;

  int mt, nt;
  tile_map(blockIdx.x, gridDim.x, M >> 7, mt, nt);
  const int m0 = mt << 7, n0 = nt << 7;
  const int kbase = blockIdx.z * K;

  const u16 *sA[4], *sB[4];
#pragma unroll
  for (int c = 0; c < 4; ++c) {
    int o = c * 4096 + w * 1024 + lane * 16;
    int r = o >> 7, s = (o >> 4) & 7;
    int ks = (s ^ (r & 7)) << 3;
    sA[c] = A + (size_t)(m0 + r) * lda + kbase + ks;
    sB[c] = B + (size_t)(n0 + r) * ldb + kbase + ks;
  }

  int aoff[2][4], boff[2][4];
#pragma unroll
  for (int kf = 0; kf < 2; ++kf)
#pragma unroll
    for (int f = 0; f < 4; ++f) {
      int ra = wr * 64 + f * 16 + l16;
      int rb = wc * 64 + f * 16 + l16;
      int sl = ((kf * 4 + lhi) ^ (l16 & 7)) << 4;
      aoff[kf][f] = ra * 128 + sl;
      boff[kf][f] = rb * 128 + sl;
    }

  f32x4 acc[4][4] = {};
  const char* pa = (const char*)As;
  const char* pb = (const char*)Bs;

  for (int k0 = 0; k0 < K; k0 += 64) {
#pragma unroll
    for (int c = 0; c < 4; ++c)
      gload_lds16(sA[c] + k0, (char*)As + c * 4096 + w * 1024);
#pragma unroll
    for (int c = 0; c < 4; ++c)
      gload_lds16(sB[c] + k0, (char*)Bs + c * 4096 + w * 1024);
    __syncthreads();
#pragma unroll
    for (int kf = 0; kf < 2; ++kf) {
      bf16x8 af[4], bf[4];
#pragma unroll
      for (int f = 0; f < 4; ++f) af[f] = *reinterpret_cast<const bf16x8*>(pa + aoff[kf][f]);
#pragma unroll
      for (int f = 0; f < 4; ++f) bf[f] = *reinterpret_cast<const bf16x8*>(pb + boff[kf][f]);
#pragma unroll
      for (int mf = 0; mf < 4; ++mf)
#pragma unroll
        for (int nf = 0; nf < 4; ++nf)
          acc[mf][nf] = __builtin_amdgcn_mfma_f32_16x16x32_bf16(af[mf], bf[nf], acc[mf][nf], 0, 0, 0);
    }
    __syncthreads();
  }

#pragma unroll
  for (int mf = 0; mf < 4; ++mf)
#pragma unroll
    for (int nf = 0; nf < 4; ++nf)
#pragma unroll
      for (int rr = 0; rr < 4; ++rr) {
        int row = m0 + wr * 64 + mf * 16 + lhi * 4 + rr;
        int col = n0 + wc * 64 + nf * 16 + l16;
        size_t idx = (size_t)row * ldc + col;
        float v = acc[mf][nf][rr];
        if (EPI == 0) Cb[idx] = f2b(v);
        else          Cf[(size_t)blockIdx.z * ((size_t)M * N) + idx] = v;
      }
}

// ---------------------------------------------------------------------------
// gemm256n: BM=256, BN=128, BK=64, 4 waves (2m x 2n), wave = 128x64 output.
// 48 KB LDS (A 32K | B 16K), (256,2), both-sides swizzle, grouped map,
// split-K via blockIdx.z. 87.5 FLOP/staged-byte, 42.7 FLOP/LDS-read-byte.
// EPI 0: Cb=bf16   3: Cf[z*M*N+idx]=acc (split-K partial)
// Requires M%256==0, N%128==0, K%64==0.
// ---------------------------------------------------------------------------
template<int EPI>
__launch_bounds__(256, 2)
__global__ void gemm256n(const u16* __restrict__ A, const u16* __restrict__ B,
                         u16* Cb, float* Cf, int M, int N, int K,
                         int lda, int ldb, int ldc) {
  __shared__ alignas(16) u16 As[256 * 64];   // 32 KB
  __shared__ alignas(16) u16 Bs[128 * 64];   // 16 KB
  const int tid = threadIdx.x;
  const int lane = tid & 63, w = tid >> 6;
  const int l16 = lane & 15, lhi = lane >> 4;
  const int wrm = w >> 1, wcn = w & 1;

  int mt, nt;
  tile_map(blockIdx.x, gridDim.x, M >> 8, mt, nt);
  const int m0 = mt << 8, n0 = nt << 7;
  const int kbase = blockIdx.z * K;

  // stage sources (pre-swizzled; 128B rows, slot ^= row&7)
  const u16 *sA[8], *sB[4];
#pragma unroll
  for (int c = 0; c < 8; ++c) {
    int o = c * 4096 + w * 1024 + lane * 16;
    int r = o >> 7, s = (o >> 4) & 7;
    int ks = (s ^ (r & 7)) << 3;
    sA[c] = A + (size_t)(m0 + r) * lda + kbase + ks;
  }
#pragma unroll
  for (int c = 0; c < 4; ++c) {
    int o = c * 4096 + w * 1024 + lane * 16;
    int r = o >> 7, s = (o >> 4) & 7;
    int ks = (s ^ (r & 7)) << 3;
    sB[c] = B + (size_t)(n0 + r) * ldb + kbase + ks;
  }

  // frag read offsets
  int aoff[2][8], boff[2][4];
#pragma unroll
  for (int kf = 0; kf < 2; ++kf) {
    const int sl = ((kf * 4 + lhi) ^ (l16 & 7)) << 4;
#pragma unroll
    for (int f = 0; f < 8; ++f)
      aoff[kf][f] = (wrm * 128 + f * 16 + l16) * 128 + sl;
#pragma unroll
    for (int f = 0; f < 4; ++f)
      boff[kf][f] = (wcn * 64 + f * 16 + l16) * 128 + sl;
  }

  f32x4 acc[8][4] = {};
  const char* pa = (const char*)As;
  const char* pb = (const char*)Bs;

  for (int k0 = 0; k0 < K; k0 += 64) {
#pragma unroll
    for (int c = 0; c < 8; ++c)
      gload_lds16(sA[c] + k0, (char*)As + c * 4096 + w * 1024);
#pragma unroll
    for (int c = 0; c < 4; ++c)
      gload_lds16(sB[c] + k0, (char*)Bs + c * 4096 + w * 1024);
    __syncthreads();
#pragma unroll
    for (int kf = 0; kf < 2; ++kf) {
      bf16x8 af[8], bf[4];
#pragma unroll
      for (int f = 0; f < 8; ++f) af[f] = *reinterpret_cast<const bf16x8*>(pa + aoff[kf][f]);
#pragma unroll
      for (int f = 0; f < 4; ++f) bf[f] = *reinterpret_cast<const bf16x8*>(pb + boff[kf][f]);
      __builtin_amdgcn_s_setprio(1);
#pragma unroll
      for (int mf = 0; mf < 8; ++mf)
#pragma unroll
        for (int nf = 0; nf < 4; ++nf)
          acc[mf][nf] = __builtin_amdgcn_mfma_f32_16x16x32_bf16(af[mf], bf[nf], acc[mf][nf], 0, 0, 0);
      __builtin_amdgcn_s_setprio(0);
    }
    __syncthreads();
  }

#pragma unroll
  for (int mf = 0; mf < 8; ++mf)
#pragma unroll
    for (int nf = 0; nf < 4; ++nf)
#pragma unroll
      for (int rr = 0; rr < 4; ++rr) {
        int row = m0 + wrm * 128 + mf * 16 + lhi * 4 + rr;
        int col = n0 + wcn * 64 + nf * 16 + l16;
        size_t idx = (size_t)row * ldc + col;
        float v = acc[mf][nf][rr];
        if (EPI == 0) Cb[idx] = f2b(v);
        else          Cf[(size_t)blockIdx.z * ((size_t)M * N) + idx] = v;
      }
}

// ---------------------------------------------------------------------------
// Fused gate+up GEMM (round-14 proven): prod = gelu(A@Bg^T)*(A@Bu^T).
// ---------------------------------------------------------------------------
__launch_bounds__(256, 2)
__global__ void gemm128gu(const u16* __restrict__ A, const u16* __restrict__ Bg,
                          const u16* __restrict__ Bu, u16* __restrict__ Cb,
                          int M, int N, int K, int lda, int ldb, int ldc) {
  __shared__ alignas(16) u16 As[128 * 64];
  __shared__ alignas(16) u16 Gs[128 * 64];
  __shared__ alignas(16) u16 Us[128 * 64];
  const int tid = threadIdx.x;
  const int lane = tid & 63, w = tid >> 6;
  const int l16 = lane & 15, lhi = lane >> 4;
  const int wr = w >> 1, wc = w & 1;

  int mt, nt;
  tile_map(blockIdx.x, gridDim.x, M >> 7, mt, nt);
  const int m0 = mt << 7, n0 = nt << 7;

  const u16 *sA[4], *sG[4], *sU[4];
#pragma unroll
  for (int c = 0; c < 4; ++c) {
    int o = c * 4096 + w * 1024 + lane * 16;
    int r = o >> 7, s = (o >> 4) & 7;
    int ks = (s ^ (r & 7)) << 3;
    sA[c] = A  + (size_t)(m0 + r) * lda + ks;
    sG[c] = Bg + (size_t)(n0 + r) * ldb + ks;
    sU[c] = Bu + (size_t)(n0 + r) * ldb + ks;
  }

  int aoff[2][4], boff[2][4];
#pragma unroll
  for (int kf = 0; kf < 2; ++kf)
#pragma unroll
    for (int f = 0; f < 4; ++f) {
      int ra = wr * 64 + f * 16 + l16;
      int rb = wc * 64 + f * 16 + l16;
      int sl = ((kf * 4 + lhi) ^ (l16 & 7)) << 4;
      aoff[kf][f] = ra * 128 + sl;
      boff[kf][f] = rb * 128 + sl;
    }

  f32x4 accG[4][4] = {};
  f32x4 accU[4][4] = {};
  const char* pa = (const char*)As;
  const char* pg = (const char*)Gs;
  const char* pu = (const char*)Us;

  for (int k0 = 0; k0 < K; k0 += 64) {
#pragma unroll
    for (int c = 0; c < 4; ++c)
      gload_lds16(sA[c] + k0, (char*)As + c * 4096 + w * 1024);
#pragma unroll
    for (int c = 0; c < 4; ++c)
      gload_lds16(sG[c] + k0, (char*)Gs + c * 4096 + w * 1024);
#pragma unroll
    for (int c = 0; c < 4; ++c)
      gload_lds16(sU[c] + k0, (char*)Us + c * 4096 + w * 1024);
    __syncthreads();
#pragma unroll
    for (int kf = 0; kf < 2; ++kf) {
      bf16x8 af[4], bf[4];
#pragma unroll
      for (int f = 0; f < 4; ++f) af[f] = *reinterpret_cast<const bf16x8*>(pa + aoff[kf][f]);
#pragma unroll
      for (int f = 0; f < 4; ++f) bf[f] = *reinterpret_cast<const bf16x8*>(pg + boff[kf][f]);
#pragma unroll
      for (int mf = 0; mf < 4; ++mf)
#pragma unroll
        for (int nf = 0; nf < 4; ++nf)
          accG[mf][nf] = __builtin_amdgcn_mfma_f32_16x16x32_bf16(af[mf], bf[nf], accG[mf][nf], 0, 0, 0);
#pragma unroll
      for (int f = 0; f < 4; ++f) bf[f] = *reinterpret_cast<const bf16x8*>(pu + boff[kf][f]);
#pragma unroll
      for (int mf = 0; mf < 4; ++mf)
#pragma unroll
        for (int nf = 0; nf < 4; ++nf)
          accU[mf][nf] = __builtin_amdgcn_mfma_f32_16x16x32_bf16(af[mf], bf[nf], accU[mf][nf], 0, 0, 0);
    }
    __syncthreads();
  }

#pragma unroll
  for (int mf = 0; mf < 4; ++mf)
#pragma unroll
    for (int nf = 0; nf < 4; ++nf)
#pragma unroll
      for (int rr = 0; rr < 4; ++rr) {
        int row = m0 + wr * 64 + mf * 16 + lhi * 4 + rr;
        int col = n0 + wc * 64 + nf * 16 + l16;
        size_t idx = (size_t)row * ldc + col;
        Cb[idx] = f2b(gelu_tanh(accG[mf][nf][rr]) * accU[mf][nf][rr]);
      }
}

// h += p0 + p1 (split-K combine)
__global__ void combine_kernel(float* __restrict__ h, const float* __restrict__ p0,
                               const float* __restrict__ p1, int n4) {
  int idx = blockIdx.x * blockDim.x + threadIdx.x;
  int stride = gridDim.x * blockDim.x;
  for (int i = idx; i < n4; i += stride) {
    f32x4 a = reinterpret_cast<f32x4*>(h)[i];
    f32x4 b = reinterpret_cast<const f32x4*>(p0)[i];
    f32x4 c = reinterpret_cast<const f32x4*>(p1)[i];
    a = a + b + c;
    reinterpret_cast<f32x4*>(h)[i] = a;
  }
}

// ---------------------------------------------------------------------------
__global__ void rope_kernel(u16* qkv, const float* __restrict__ cosT, const float* __restrict__ sinT) {
  const int s = blockIdx.x, b = blockIdx.y;
  const size_t base = (size_t)(b * S_LEN + s) * QKV_N;
  for (int i = threadIdx.x; i < 9 * 128; i += 256) {
    int hh = i >> 7, d = i & 127;
    size_t off = base + (hh < 8 ? hh * 256 : 2048) + d;
    float x1 = b2f(qkv[off]), x2 = b2f(qkv[off + 128]);
    float c = cosT[s * 128 + d], sn = sinT[s * 128 + d];
    qkv[off]       = f2b(x1 * c - x2 * sn);
    qkv[off + 128] = f2b(x1 * sn + x2 * c);
  }
}

// ---------------------------------------------------------------------------
__global__ void vtrans_kernel(const u16* __restrict__ qkv, u16* __restrict__ vT) {
  __shared__ u16 t[64][65];
  const int s0 = blockIdx.x * 64, d0 = blockIdx.y * 64, b = blockIdx.z;
  for (int i = threadIdx.x; i < 4096; i += 256) {
    int r = i >> 6, c = i & 63;
    t[r][c] = qkv[(size_t)(b * S_LEN + s0 + r) * QKV_N + 2304 + d0 + c];
  }
  __syncthreads();
  for (int i = threadIdx.x; i < 4096; i += 256) {
    int r = i >> 6, c = i & 63;
    vT[(size_t)(b * HD + d0 + r) * S_LEN + s0 + c] = t[c][r];
  }
}

// ---------------------------------------------------------------------------
// Flash attention (round-11 proven): LDS-staged K/V^T, KVBLK=32, prefetch-2.
// ---------------------------------------------------------------------------
#define VMW(N) asm volatile("s_waitcnt vmcnt(" #N ")" ::: "memory")

__launch_bounds__(256)
__global__ void flash_kernel(const u16* __restrict__ qkv, const u16* __restrict__ vT,
                             u16* __restrict__ outp) {
  extern __shared__ char fsm[];
  const int qt = blockIdx.x, hh = blockIdx.y, b = blockIdx.z;
  const int tid = threadIdx.x, lane = tid & 63, w = tid >> 6;
  const int l16 = lane & 15, lhi = lane >> 4;

  const u16* srcK[4]; const u16* srcV[4];
#pragma unroll
  for (int c = 0; c < 4; ++c) {
    int o = c * 4096 + tid * 16;
    int rK = o >> 9, sK = (o >> 4) & 31;
    srcK[c] = qkv + (size_t)(b * S_LEN + rK) * QKV_N + HDIM + ((sK ^ (rK & 7)) << 3);
    int dV = o >> 6, sV = (o >> 4) & 3;
    srcV[c] = vT + (size_t)(b * HD + dV) * S_LEN + ((sV ^ ((dV >> 1) & 3)) << 3);
  }
  const size_t KSTEP = (size_t)32 * QKV_N;

  u16* plds = (u16*)(fsm + 65536) + w * 640;

  bf16x8 aq[8];
  {
    const u16* qp = qkv + (size_t)(b * S_LEN + qt * 64 + w * 16 + l16) * QKV_N + hh * HD + lhi * 8;
#pragma unroll
    for (int kf = 0; kf < 8; ++kf)
      aq[kf] = *reinterpret_cast<const bf16x8*>(qp + kf * 32);
  }

  f32x4 oacc[16] = {};
  float mrow[4] = {-1e30f, -1e30f, -1e30f, -1e30f};
  float lrow[4] = {0.f, 0.f, 0.f, 0.f};
  const int rowg0 = qt * 64 + w * 16 + lhi * 4;
  const int NT = 2 * (qt + 1);
  const int m7 = l16 & 7;
  const int vcol = (lhi ^ ((l16 >> 1) & 3)) << 4;

  auto stage = [&](int t) {
    char* kb = fsm + (t & 1) * 16384;
    char* vb = fsm + 32768 + (t & 1) * 16384;
#pragma unroll
    for (int c = 0; c < 4; ++c) {
      gload_lds16(srcK[c] + (size_t)t * KSTEP, kb + c * 4096 + w * 1024);
      gload_lds16(srcV[c] + t * 32,            vb + c * 4096 + w * 1024);
    }
  };

  stage(0);
  stage(1);
  VMW(8);
  barrier_raw();

  for (int t = 0; t < NT; ++t) {
    const char* kb = fsm + (t & 1) * 16384;
    const char* vb = fsm + 32768 + (t & 1) * 16384;
    const int j0 = t * 32;

    f32x4 sacc[2] = {};
#pragma unroll
    for (int nf = 0; nf < 2; ++nf) {
      const char* rowp = kb + (nf * 16 + l16) * 512;
#pragma unroll
      for (int kf = 0; kf < 8; ++kf) {
        bf16x8 bk = *reinterpret_cast<const bf16x8*>(rowp + ((((kf << 2) + lhi) ^ m7) << 4));
        sacc[nf] = __builtin_amdgcn_mfma_f32_16x16x32_bf16(aq[kf], bk, sacc[nf], 0, 0, 0);
      }
    }

    float sval[2][4];
    float tm[4] = {-1e30f, -1e30f, -1e30f, -1e30f};
#pragma unroll
    for (int nf = 0; nf < 2; ++nf) {
      int colg = j0 + nf * 16 + l16;
#pragma unroll
      for (int r = 0; r < 4; ++r) {
        float sv = sacc[nf][r] * ATT_SCALE;
        if (colg > rowg0 + r) sv = -1e30f;
        sval[nf][r] = sv;
        tm[r] = fmaxf(tm[r], sv);
      }
    }
#pragma unroll
    for (int off = 1; off < 16; off <<= 1)
#pragma unroll
      for (int r = 0; r < 4; ++r) tm[r] = fmaxf(tm[r], __shfl_xor(tm[r], off));

    float alpha[4], psum[4] = {0.f, 0.f, 0.f, 0.f};
#pragma unroll
    for (int r = 0; r < 4; ++r) {
      float mn = fmaxf(mrow[r], tm[r]);
      alpha[r] = __expf(mrow[r] - mn);
      mrow[r] = mn;
    }
#pragma unroll
    for (int nf = 0; nf < 2; ++nf)
#pragma unroll
      for (int r = 0; r < 4; ++r) {
        float p = __expf(sval[nf][r] - mrow[r]);
        psum[r] += p;
        plds[(lhi * 4 + r) * 40 + nf * 16 + l16] = f2b(p);
      }
#pragma unroll
    for (int off = 1; off < 16; off <<= 1)
#pragma unroll
      for (int r = 0; r < 4; ++r) psum[r] += __shfl_xor(psum[r], off);
#pragma unroll
    for (int r = 0; r < 4; ++r) lrow[r] = lrow[r] * alpha[r] + psum[r];
#pragma unroll
    for (int nf2 = 0; nf2 < 16; ++nf2)
#pragma unroll
      for (int r = 0; r < 4; ++r) oacc[nf2][r] *= alpha[r];

    {
      bf16x8 pa = *reinterpret_cast<const bf16x8*>((const char*)plds + l16 * 80 + lhi * 16);
#pragma unroll
      for (int nf2 = 0; nf2 < 16; ++nf2) {
        bf16x8 bv = *reinterpret_cast<const bf16x8*>(vb + (nf2 * 16 + l16) * 64 + vcol);
        oacc[nf2] = __builtin_amdgcn_mfma_f32_16x16x32_bf16(pa, bv, oacc[nf2], 0, 0, 0);
      }
    }

    if (t + 1 < NT) {
      barrier_raw();
      if (t + 2 < NT) {
        stage(t + 2);
        VMW(8);
      } else {
        VMW(0);
      }
      barrier_raw();
    }
  }

  float inv[4];
#pragma unroll
  for (int r = 0; r < 4; ++r) inv[r] = 1.0f / lrow[r];
#pragma unroll
  for (int nf2 = 0; nf2 < 16; ++nf2)
#pragma unroll
    for (int r = 0; r < 4; ++r) {
      size_t idx = (size_t)(b * S_LEN + rowg0 + r) * HDIM + hh * HD + nf2 * 16 + l16;
      outp[idx] = f2b(oacc[nf2][r] * inv[r]);
    }
}

// ---------------------------------------------------------------------------
extern "C" void kernel_launch(void* const* d_in, const int* in_sizes, int n_in,
                              void* d_out, int out_size, void* d_ws, size_t ws_size,
                              hipStream_t stream) {
  const float* hidden = (const float*)d_in[0];
  const float* cosT   = (const float*)d_in[1];
  const float* sinT   = (const float*)d_in[2];
  const float* wq  = (const float*)d_in[6];
  const float* wk  = (const float*)d_in[7];
  const float* wv  = (const float*)d_in[8];
  const float* wo  = (const float*)d_in[9];
  const float* wg  = (const float*)d_in[10];
  const float* wu  = (const float*)d_in[11];
  const float* wd  = (const float*)d_in[12];
  const float* ln1 = (const float*)d_in[13];
  const float* ln2 = (const float*)d_in[14];
  const float* nw  = (const float*)d_in[15];
  float* h = (float*)d_out;

  // ws layout (u16 elems): W 67.1M | xbf 8.4M | qkv 10.5M | vT 1.05M | attno 8.4M | gate 67.1M
  u16* W     = (u16*)d_ws;
  u16* xbf   = W + 67108864ull;
  u16* qkv   = xbf + 8388608ull;
  u16* vTb   = qkv + 10485760ull;
  u16* attno = vTb + 1048576ull;
  u16* gateb = attno + 8388608ull;
  float* pbuf = (float*)(W + 33554432ull);  // split-K partials (2 x 8.4M f32)

  hipFuncSetAttribute(reinterpret_cast<const void*>(flash_kernel), hipFuncAttributeMaxDynamicSharedMemorySize, 70656);

  hipMemcpyAsync(h, hidden, sizeof(float) * 8388608ull, hipMemcpyDeviceToDevice, stream);

  auto cvt = [&](const float* src, u16* dst, long n) {
    int n4 = (int)(n >> 2);
    int blocks = (n4 + 255) / 256;
    if (blocks > 2048) blocks = 2048;
    cvt_kernel<<<blocks, 256, 0, stream>>>(src, dst, n4);
  };

  for (int l = 0; l < 2; ++l) {
    const float* lwq = wq + (size_t)l * 2048 * 2048;
    const float* lwk = wk + (size_t)l * 256 * 2048;
    const float* lwv = wv + (size_t)l * 256 * 2048;
    const float* lwo = wo + (size_t)l * 2048 * 2048;
    const float* lwg = wg + (size_t)l * 16384 * 2048;
    const float* lwu = wu + (size_t)l * 16384 * 2048;
    const float* lwd = wd + (size_t)l * 2048 * 16384;

    // x = rms(h, ln1)
    rms_kernel<true><<<4096, 256, 0, stream>>>(h, ln1 + l * 2048, xbf, nullptr);

    // fused qkv projection
    cvt(lwq, W, 4194304);
    cvt(lwk, W + 4194304, 524288);
    cvt(lwv, W + 4718592, 524288);
    gemm128<0><<<dim3(32 * 20, 1, 1), 256, 0, stream>>>(xbf, W, qkv, nullptr,
                                                        4096, 2560, 2048, 2048, 2048, 2560);

    rope_kernel<<<dim3(2048, 2), 256, 0, stream>>>(qkv, cosT, sinT);
    vtrans_kernel<<<dim3(32, 4, 2), 256, 0, stream>>>(qkv, vTb);
    flash_kernel<<<dim3(32, 8, 2), 256, 70656, stream>>>(qkv, vTb, attno);

    // h += attn_out @ wo^T   (gemm256n split-K x2 -> partials -> combine)
    cvt(lwo, W, 4194304);
    gemm256n<3><<<dim3(16 * 16, 1, 2), 256, 0, stream>>>(attno, W, nullptr, pbuf,
                                                         4096, 2048, 1024, 2048, 2048, 2048);
    combine_kernel<<<2048, 256, 0, stream>>>(h, pbuf, pbuf + 8388608ull, 2097152);

    // x = rms(h, ln2)
    rms_kernel<true><<<4096, 256, 0, stream>>>(h, ln2 + l * 2048, xbf, nullptr);

    // prod = gelu(x @ wg^T) * (x @ wu^T)   (fused, grouped map 32x128)
    cvt(lwg, W, 33554432);
    cvt(lwu, W + 33554432, 33554432);
    gemm128gu<<<dim3(32 * 128, 1, 1), 256, 0, stream>>>(xbf, W, W + 33554432, gateb,
                                                        4096, 16384, 2048, 2048, 2048, 16384);

    // h += prod @ wd^T  (gemm256n split-K x2 -> partials -> combine)
    cvt(lwd, W, 33554432);
    gemm256n<3><<<dim3(16 * 16, 1, 2), 256, 0, stream>>>(gateb, W, nullptr, pbuf,
                                                         4096, 2048, 8192, 16384, 16384, 2048);
    combine_kernel<<<2048, 256, 0, stream>>>(h, pbuf, pbuf + 8388608ull, 2097152);
  }

  // final norm (in place, f32 out)
  rms_kernel<false><<<4096, 256, 0, stream>>>(h, nw, nullptr, h);
}